// Round 3
// baseline (842.064 us; speedup 1.0000x reference)
//
#include <hip/hip_runtime.h>
#include <hip/hip_bf16.h>
#include <math.h>

#define N_NODES  50000
#define N_EDGES  800000
#define IN_DIM   128
#define HID      256
#define FC1      1024
#define FC2      512
#define N_ACT    16
#define N_AGENTS 8192

typedef short bf16x8 __attribute__((ext_vector_type(8)));
typedef float floatx4 __attribute__((ext_vector_type(4)));

__device__ __forceinline__ unsigned short f2b(float f) {
    union { float f; unsigned int i; } v;
    v.f = f;
    unsigned int lsb = (v.i >> 16) & 1u;
    v.i += 0x7fffu + lsb;            // round-to-nearest-even
    return (unsigned short)(v.i >> 16);
}

__device__ __forceinline__ float b2f(unsigned short u) {
    union { unsigned int i; float f; } v;
    v.i = ((unsigned int)u) << 16;
    return v.f;
}

// ---- init: deg=0, slot=-1, h_acc=0 (ws is 0xAA-poisoned each call) ----
__global__ __launch_bounds__(256) void init_k(int* deg, int* slot, float* h_acc) {
    int i = blockIdx.x * 256 + threadIdx.x;
    if (i < N_NODES) { deg[i] = 0; slot[i] = -1; }
    if (i < N_AGENTS * HID) h_acc[i] = 0.0f;
}

// ---- claim: first agent touching node n owns a slot ----
__global__ __launch_bounds__(256) void claim_k(const int* agent_idx, int* slot) {
    int i = blockIdx.x * 256 + threadIdx.x;
    if (i < N_AGENTS) {
        int n = agent_idx[i];
        atomicCAS(&slot[n], -1, i);
    }
}

// ---- in-degree over real edges ----
__global__ __launch_bounds__(256) void degree_k(const int* dst, int* deg) {
    int e = blockIdx.x * 256 + threadIdx.x;
    if (e < N_EDGES) atomicAdd(&deg[dst[e]], 1);
}

// ---- dis = rsqrt(deg + 1)  (self-loop included) ----
__global__ __launch_bounds__(256) void dis_k(const int* deg, float* dis) {
    int i = blockIdx.x * 256 + threadIdx.x;
    if (i < N_NODES) dis[i] = rsqrtf((float)(deg[i] + 1));
}

// ---- convert f32 -> bf16 (for x) ----
__global__ __launch_bounds__(256) void cvt_k(const float* in, unsigned short* out, int n) {
    int i = blockIdx.x * 256 + threadIdx.x;
    if (i < n) out[i] = f2b(in[i]);
}

// ---- transpose + convert: f32 [K,N] -> bf16 [N,K] ----
__global__ __launch_bounds__(256) void tcvt_k(const float* in, unsigned short* out,
                                              int K, int N) {
    int i = blockIdx.x * 256 + threadIdx.x;
    if (i < K * N) {
        int k = i / N;
        int n = i - k * N;
        out[n * K + k] = f2b(in[i]);
    }
}

// ---- GEMM: C[M,N] = A[M,K] @ Bt[N,K]^T, one wave per 16x16 tile, bf16 MFMA ----
// mode 0: store bf16(v)                to outb   (xw, no bias)
// mode 1: store f32  (v + bias)        to outf   (pre-layernorm)
// mode 2: store f32  sigmoid(v + bias) to outf   (head)
__global__ __launch_bounds__(256) void gemm_k(const unsigned short* __restrict__ A,
                                              const unsigned short* __restrict__ Bt,
                                              const float* __restrict__ bias,
                                              unsigned short* __restrict__ outb,
                                              float* __restrict__ outf,
                                              int M, int N, int K, int mode) {
    int wave = threadIdx.x >> 6;
    int lane = threadIdx.x & 63;
    int tiles_n = N >> 4;
    int tiles = (M >> 4) * tiles_n;
    int tile = blockIdx.x * 4 + wave;
    if (tile >= tiles) return;
    int tm = tile / tiles_n;
    int tn = tile - tm * tiles_n;
    int r16 = lane & 15;
    int quad = lane >> 4;
    const bf16x8* pa = (const bf16x8*)(A + (size_t)(tm * 16 + r16) * K + quad * 8);
    const bf16x8* pb = (const bf16x8*)(Bt + (size_t)(tn * 16 + r16) * K + quad * 8);
    floatx4 acc = {0.0f, 0.0f, 0.0f, 0.0f};
    int ksteps = K >> 5;
    for (int s = 0; s < ksteps; ++s) {
        bf16x8 a = pa[4 * s];   // advance 32 bf16 per step
        bf16x8 b = pb[4 * s];
        acc = __builtin_amdgcn_mfma_f32_16x16x32_bf16(a, b, acc, 0, 0, 0);
    }
    // C/D layout: col = lane&15, row = quad*4 + r
    int ocol = tn * 16 + r16;
    float bv = 0.0f;
    if (mode != 0) bv = bias[ocol];
    for (int r = 0; r < 4; ++r) {
        int orow = tm * 16 + quad * 4 + r;
        size_t idx = (size_t)orow * N + ocol;
        float v = acc[r];
        if (mode == 0) {
            outb[idx] = f2b(v);
        } else if (mode == 1) {
            outf[idx] = v + bv;
        } else {
            v += bv;
            outf[idx] = 1.0f / (1.0f + expf(-v));
        }
    }
}

// ---- edge scatter: one wave per edge; skip edges whose dst has no slot ----
__global__ __launch_bounds__(256) void scatter_k(const int* __restrict__ src,
                                                 const int* __restrict__ dst,
                                                 const float* __restrict__ dis,
                                                 const int* __restrict__ slot,
                                                 const unsigned short* __restrict__ xw,
                                                 float* __restrict__ h_acc) {
    int lane = threadIdx.x & 63;
    int e = blockIdx.x * 4 + (threadIdx.x >> 6);
    if (e >= N_EDGES) return;
    int d = dst[e];
    int sl = slot[d];
    if (sl < 0) return;               // wave-uniform skip (~85% of edges)
    int s = src[e];
    float w = dis[s] * dis[d];
    ushort4 u = *(const ushort4*)(xw + (size_t)s * HID + lane * 4);
    float* hr = h_acc + (size_t)sl * HID + lane * 4;
    atomicAdd(hr + 0, w * b2f(u.x));
    atomicAdd(hr + 1, w * b2f(u.y));
    atomicAdd(hr + 2, w * b2f(u.z));
    atomicAdd(hr + 3, w * b2f(u.w));
}

// ---- gather per agent: edge acc + self-loop + bias, relu -> bf16 ----
__global__ __launch_bounds__(256) void gather_k(const int* __restrict__ agent_idx,
                                                const int* __restrict__ slot,
                                                const float* __restrict__ h_acc,
                                                const unsigned short* __restrict__ xw,
                                                const float* __restrict__ dis,
                                                const float* __restrict__ bgcn,
                                                unsigned short* __restrict__ h0) {
    int a = blockIdx.x;
    int c = threadIdx.x;              // HID == 256 == blockDim
    int n = agent_idx[a];
    int sl = slot[n];
    float dn = dis[n];
    float v = h_acc[(size_t)sl * HID + c]
            + b2f(xw[(size_t)n * HID + c]) * dn * dn
            + bgcn[c];
    if (v < 0.0f) v = 0.0f;
    h0[(size_t)a * HID + c] = f2b(v);
}

// ---- row LayerNorm (+affine) + relu, f32 in -> bf16 out ----
__global__ __launch_bounds__(256) void ln_relu_k(const float* __restrict__ z,
                                                 const float* __restrict__ g,
                                                 const float* __restrict__ be,
                                                 unsigned short* __restrict__ out, int L) {
    size_t base = (size_t)blockIdx.x * L;
    float s = 0.0f, s2 = 0.0f;
    for (int c = threadIdx.x; c < L; c += 256) {
        float v = z[base + c];
        s += v;
        s2 += v * v;
    }
    for (int off = 32; off > 0; off >>= 1) {
        s += __shfl_down(s, off);
        s2 += __shfl_down(s2, off);
    }
    __shared__ float red[8];
    int wave = threadIdx.x >> 6;
    int lane = threadIdx.x & 63;
    if (lane == 0) { red[wave] = s; red[4 + wave] = s2; }
    __syncthreads();
    s  = red[0] + red[1] + red[2] + red[3];
    s2 = red[4] + red[5] + red[6] + red[7];
    float invL = 1.0f / (float)L;
    float mean = s * invL;
    float var = s2 * invL - mean * mean;
    float inv = rsqrtf(var + 1e-5f);
    for (int c = threadIdx.x; c < L; c += 256) {
        float v = (z[base + c] - mean) * inv * g[c] + be[c];
        if (v < 0.0f) v = 0.0f;
        out[base + c] = f2b(v);
    }
}

extern "C" void kernel_launch(void* const* d_in, const int* in_sizes, int n_in,
                              void* d_out, int out_size, void* d_ws, size_t ws_size,
                              hipStream_t stream) {
    const float* x    = (const float*)d_in[0];
    const int*   ei   = (const int*)d_in[1];
    const int*   agent= (const int*)d_in[2];
    const float* Wgcn = (const float*)d_in[3];
    const float* bgcn = (const float*)d_in[4];
    const float* W1   = (const float*)d_in[5];
    const float* b1   = (const float*)d_in[6];
    const float* g1   = (const float*)d_in[7];
    const float* be1  = (const float*)d_in[8];
    const float* W2   = (const float*)d_in[9];
    const float* b2   = (const float*)d_in[10];
    const float* g2   = (const float*)d_in[11];
    const float* be2  = (const float*)d_in[12];
    const float* Wmu  = (const float*)d_in[13];
    const float* bmu  = (const float*)d_in[14];
    float* out = (float*)d_out;

    const int* srcp = ei;
    const int* dstp = ei + N_EDGES;

    // workspace layout (all offsets 256B aligned)
    char* ws = (char*)d_ws;
    size_t off = 0;
    int* deg = (int*)(ws + off);                 off += ((size_t)N_NODES * 4 + 255) & ~(size_t)255;
    float* dis = (float*)(ws + off);             off += ((size_t)N_NODES * 4 + 255) & ~(size_t)255;
    int* slot = (int*)(ws + off);                off += ((size_t)N_NODES * 4 + 255) & ~(size_t)255;
    unsigned short* xb     = (unsigned short*)(ws + off); off += ((size_t)N_NODES * IN_DIM * 2 + 255) & ~(size_t)255;
    unsigned short* wgcn_t = (unsigned short*)(ws + off); off += ((size_t)IN_DIM * HID * 2 + 255) & ~(size_t)255;
    unsigned short* w1_t   = (unsigned short*)(ws + off); off += ((size_t)HID * FC1 * 2 + 255) & ~(size_t)255;
    unsigned short* w2_t   = (unsigned short*)(ws + off); off += ((size_t)FC1 * FC2 * 2 + 255) & ~(size_t)255;
    unsigned short* wmu_t  = (unsigned short*)(ws + off); off += ((size_t)FC2 * N_ACT * 2 + 255) & ~(size_t)255;
    unsigned short* xw     = (unsigned short*)(ws + off); off += ((size_t)N_NODES * HID * 2 + 255) & ~(size_t)255;
    float* h_acc = (float*)(ws + off);           off += ((size_t)N_AGENTS * HID * 4 + 255) & ~(size_t)255;
    unsigned short* h0 = (unsigned short*)(ws + off); off += ((size_t)N_AGENTS * HID * 2 + 255) & ~(size_t)255;
    float* z = (float*)(ws + off);               off += ((size_t)N_AGENTS * FC1 * 4 + 255) & ~(size_t)255;
    unsigned short* h1 = (unsigned short*)(ws + off); off += ((size_t)N_AGENTS * FC1 * 2 + 255) & ~(size_t)255;
    unsigned short* h2 = (unsigned short*)(ws + off); off += ((size_t)N_AGENTS * FC2 * 2 + 255) & ~(size_t)255;

    // graph prep
    init_k<<<(N_AGENTS * HID) / 256, 256, 0, stream>>>(deg, slot, h_acc);
    claim_k<<<(N_AGENTS + 255) / 256, 256, 0, stream>>>(agent, slot);
    degree_k<<<(N_EDGES + 255) / 256, 256, 0, stream>>>(dstp, deg);
    dis_k<<<(N_NODES + 255) / 256, 256, 0, stream>>>(deg, dis);

    // convert x, transpose+convert weights -> bf16
    cvt_k<<<(N_NODES * IN_DIM + 255) / 256, 256, 0, stream>>>(x, xb, N_NODES * IN_DIM);
    tcvt_k<<<(IN_DIM * HID + 255) / 256, 256, 0, stream>>>(Wgcn, wgcn_t, IN_DIM, HID);
    tcvt_k<<<(HID * FC1 + 255) / 256, 256, 0, stream>>>(W1, w1_t, HID, FC1);
    tcvt_k<<<(FC1 * FC2 + 255) / 256, 256, 0, stream>>>(W2, w2_t, FC1, FC2);
    tcvt_k<<<(FC2 * N_ACT + 255) / 256, 256, 0, stream>>>(Wmu, wmu_t, FC2, N_ACT);

    // xw = x @ W_gcn   [50000,128] @ [128,256] -> bf16
    {
        int tiles = (N_NODES / 16) * (HID / 16);
        gemm_k<<<(tiles + 3) / 4, 256, 0, stream>>>(xb, wgcn_t, (const float*)0,
                                                    xw, (float*)0, N_NODES, HID, IN_DIM, 0);
    }

    // edge scatter into needed slots (f32 accumulation)
    scatter_k<<<(N_EDGES + 3) / 4, 256, 0, stream>>>(srcp, dstp, dis, slot, xw, h_acc);

    // gather agents + self-loop + bias + relu
    gather_k<<<N_AGENTS, 256, 0, stream>>>(agent, slot, h_acc, xw, dis, bgcn, h0);

    // FC1 -> LN+relu
    {
        int tiles = (N_AGENTS / 16) * (FC1 / 16);
        gemm_k<<<(tiles + 3) / 4, 256, 0, stream>>>(h0, w1_t, b1, (unsigned short*)0, z,
                                                    N_AGENTS, FC1, HID, 1);
        ln_relu_k<<<N_AGENTS, 256, 0, stream>>>(z, g1, be1, h1, FC1);
    }

    // FC2 -> LN+relu
    {
        int tiles = (N_AGENTS / 16) * (FC2 / 16);
        gemm_k<<<(tiles + 3) / 4, 256, 0, stream>>>(h1, w2_t, b2, (unsigned short*)0, z,
                                                    N_AGENTS, FC2, FC1, 1);
        ln_relu_k<<<N_AGENTS, 256, 0, stream>>>(z, g2, be2, h2, FC2);
    }

    // head: sigmoid(h2 @ Wmu + bmu) -> f32 out
    {
        int tiles = (N_AGENTS / 16) * (N_ACT / 16);
        gemm_k<<<(tiles + 3) / 4, 256, 0, stream>>>(h2, wmu_t, bmu, (unsigned short*)0, out,
                                                    N_AGENTS, N_ACT, FC2, 2);
    }
}

// Round 4
// 509.939 us; speedup vs baseline: 1.6513x; 1.6513x over previous
//
#include <hip/hip_runtime.h>
#include <hip/hip_bf16.h>
#include <math.h>

#define N_NODES  50000
#define N_EDGES  800000
#define IN_DIM   128
#define HID      256
#define FC1      1024
#define FC2      512
#define N_ACT    16
#define N_AGENTS 8192

typedef short bf16x8 __attribute__((ext_vector_type(8)));
typedef float floatx4 __attribute__((ext_vector_type(4)));

__device__ __forceinline__ unsigned short f2b(float f) {
    union { float f; unsigned int i; } v;
    v.f = f;
    unsigned int lsb = (v.i >> 16) & 1u;
    v.i += 0x7fffu + lsb;            // round-to-nearest-even
    return (unsigned short)(v.i >> 16);
}

__device__ __forceinline__ float b2f(unsigned short u) {
    union { unsigned int i; float f; } v;
    v.i = ((unsigned int)u) << 16;
    return v.f;
}

// ---- init: deg=0, mark=-1, fill=0, cnt=0 ----
__global__ __launch_bounds__(256) void init_k(int* deg, int* nid, int* fill, int* cnt) {
    int i = blockIdx.x * 256 + threadIdx.x;
    if (i < N_NODES) { deg[i] = 0; nid[i] = -1; }
    if (i < N_AGENTS) fill[i] = 0;
    if (i == 0) *cnt = 0;
}

// ---- claim: mark nodes referenced by any agent ----
__global__ __launch_bounds__(256) void claim_k(const int* agent_idx, int* nid) {
    int i = blockIdx.x * 256 + threadIdx.x;
    if (i < N_AGENTS) {
        int n = agent_idx[i];
        atomicCAS(&nid[n], -1, i);
    }
}

// ---- compact: assign compact ids to marked nodes ----
__global__ __launch_bounds__(256) void compact_k(int* nid, int* list, int* cnt) {
    int i = blockIdx.x * 256 + threadIdx.x;
    if (i < N_NODES) {
        if (nid[i] != -1) {
            int c = atomicAdd(cnt, 1);
            nid[i] = c;
            list[c] = i;
        }
    }
}

// ---- in-degree over real edges (int atomics) ----
__global__ __launch_bounds__(256) void degree_k(const int* dst, int* deg) {
    int e = blockIdx.x * 256 + threadIdx.x;
    if (e < N_EDGES) atomicAdd(&deg[dst[e]], 1);
}

// ---- dis = rsqrt(deg + 1)  (self-loop included) ----
__global__ __launch_bounds__(256) void dis_k(const int* deg, float* dis) {
    int i = blockIdx.x * 256 + threadIdx.x;
    if (i < N_NODES) dis[i] = rsqrtf((float)(deg[i] + 1));
}

// ---- exclusive scan of row lengths (deg[list[c]]) over cnt rows, 1 block ----
__global__ __launch_bounds__(256) void scan_k(const int* deg, const int* list,
                                              const int* cntp, int* rowoff) {
    __shared__ int buf[256];
    __shared__ int base_s;
    int n = *cntp;
    int tid = threadIdx.x;
    if (tid == 0) base_s = 0;
    __syncthreads();
    for (int start = 0; start < n; start += 256) {
        int c = start + tid;
        int v = (c < n) ? deg[list[c]] : 0;
        buf[tid] = v;
        __syncthreads();
        for (int o = 1; o < 256; o <<= 1) {
            int t = (tid >= o) ? buf[tid - o] : 0;
            __syncthreads();
            buf[tid] += t;
            __syncthreads();
        }
        int incl = buf[tid];
        int base = base_s;
        if (c < n) rowoff[c] = base + incl - v;     // exclusive
        __syncthreads();
        if (tid == 255) base_s = base + incl;
        __syncthreads();
    }
    if (tid == 0) rowoff[n] = base_s;
}

// ---- fill buckets: for needed dsts, append src to its row ----
__global__ __launch_bounds__(256) void fill_k(const int* __restrict__ src,
                                              const int* __restrict__ dst,
                                              const int* __restrict__ nid,
                                              const int* __restrict__ rowoff,
                                              int* __restrict__ fill,
                                              int* __restrict__ ebuf) {
    int e = blockIdx.x * 256 + threadIdx.x;
    if (e >= N_EDGES) return;
    int c = nid[dst[e]];
    if (c < 0) return;
    int p = atomicAdd(&fill[c], 1);
    ebuf[rowoff[c] + p] = src[e];
}

// ---- accumulate per needed node: sum in-edges + self-loop + bias, relu -> bf16 ----
__global__ __launch_bounds__(256) void accum_k(const int* __restrict__ cntp,
                                               const int* __restrict__ list,
                                               const int* __restrict__ rowoff,
                                               const int* __restrict__ ebuf,
                                               const float* __restrict__ dis,
                                               const unsigned short* __restrict__ xw,
                                               const float* __restrict__ bgcn,
                                               unsigned short* __restrict__ h_node) {
    int c = blockIdx.x;
    if (c >= *cntp) return;
    int n = list[c];
    int lane = threadIdx.x & 63;
    int wave = threadIdx.x >> 6;
    int beg = rowoff[c], end = rowoff[c + 1];
    float dn = dis[n];
    floatx4 acc = {0.0f, 0.0f, 0.0f, 0.0f};
    for (int i = beg + wave; i < end; i += 4) {
        int s = ebuf[i];
        float w = dis[s] * dn;
        ushort4 u = *(const ushort4*)(xw + (size_t)s * HID + lane * 4);
        acc.x += w * b2f(u.x);
        acc.y += w * b2f(u.y);
        acc.z += w * b2f(u.z);
        acc.w += w * b2f(u.w);
    }
    __shared__ float part[4][HID];
    part[wave][lane * 4 + 0] = acc.x;
    part[wave][lane * 4 + 1] = acc.y;
    part[wave][lane * 4 + 2] = acc.z;
    part[wave][lane * 4 + 3] = acc.w;
    __syncthreads();
    int t = threadIdx.x;   // channel 0..255
    float v = part[0][t] + part[1][t] + part[2][t] + part[3][t];
    v += b2f(xw[(size_t)n * HID + t]) * dn * dn + bgcn[t];
    if (v < 0.0f) v = 0.0f;
    h_node[(size_t)c * HID + t] = f2b(v);
}

// ---- gather per agent: copy its node's bf16 row ----
__global__ __launch_bounds__(256) void gather_k(const int* __restrict__ agent_idx,
                                                const int* __restrict__ nid,
                                                const unsigned short* __restrict__ h_node,
                                                unsigned short* __restrict__ h0) {
    int a = blockIdx.x;
    int t = threadIdx.x;
    int c = nid[agent_idx[a]];
    h0[(size_t)a * HID + t] = h_node[(size_t)c * HID + t];
}

// ---- convert f32 -> bf16 (for x) ----
__global__ __launch_bounds__(256) void cvt_k(const float* in, unsigned short* out, int n) {
    int i = blockIdx.x * 256 + threadIdx.x;
    if (i < n) out[i] = f2b(in[i]);
}

// ---- transpose + convert: f32 [K,N] -> bf16 [N,K] ----
__global__ __launch_bounds__(256) void tcvt_k(const float* in, unsigned short* out,
                                              int K, int N) {
    int i = blockIdx.x * 256 + threadIdx.x;
    if (i < K * N) {
        int k = i / N;
        int n = i - k * N;
        out[n * K + k] = f2b(in[i]);
    }
}

// ---- GEMM: C[M,N] = A[M,K] @ Bt[N,K]^T, one wave per 16x16 tile, bf16 MFMA ----
// mode 0: store bf16(v)                to outb   (xw, no bias)
// mode 1: store f32  (v + bias)        to outf   (pre-layernorm)
// mode 2: store f32  sigmoid(v + bias) to outf   (head)
__global__ __launch_bounds__(256) void gemm_k(const unsigned short* __restrict__ A,
                                              const unsigned short* __restrict__ Bt,
                                              const float* __restrict__ bias,
                                              unsigned short* __restrict__ outb,
                                              float* __restrict__ outf,
                                              int M, int N, int K, int mode) {
    int wave = threadIdx.x >> 6;
    int lane = threadIdx.x & 63;
    int tiles_n = N >> 4;
    int tiles = (M >> 4) * tiles_n;
    int tile = blockIdx.x * 4 + wave;
    if (tile >= tiles) return;
    int tm = tile / tiles_n;
    int tn = tile - tm * tiles_n;
    int r16 = lane & 15;
    int quad = lane >> 4;
    const bf16x8* pa = (const bf16x8*)(A + (size_t)(tm * 16 + r16) * K + quad * 8);
    const bf16x8* pb = (const bf16x8*)(Bt + (size_t)(tn * 16 + r16) * K + quad * 8);
    floatx4 acc = {0.0f, 0.0f, 0.0f, 0.0f};
    int ksteps = K >> 5;
    for (int s = 0; s < ksteps; ++s) {
        bf16x8 a = pa[4 * s];
        bf16x8 b = pb[4 * s];
        acc = __builtin_amdgcn_mfma_f32_16x16x32_bf16(a, b, acc, 0, 0, 0);
    }
    // C/D layout: col = lane&15, row = quad*4 + r
    int ocol = tn * 16 + r16;
    float bv = 0.0f;
    if (mode != 0) bv = bias[ocol];
    for (int r = 0; r < 4; ++r) {
        int orow = tm * 16 + quad * 4 + r;
        size_t idx = (size_t)orow * N + ocol;
        float v = acc[r];
        if (mode == 0) {
            outb[idx] = f2b(v);
        } else if (mode == 1) {
            outf[idx] = v + bv;
        } else {
            v += bv;
            outf[idx] = 1.0f / (1.0f + expf(-v));
        }
    }
}

// ---- row LayerNorm (+affine) + relu, f32 in -> bf16 out ----
__global__ __launch_bounds__(256) void ln_relu_k(const float* __restrict__ z,
                                                 const float* __restrict__ g,
                                                 const float* __restrict__ be,
                                                 unsigned short* __restrict__ out, int L) {
    size_t base = (size_t)blockIdx.x * L;
    float s = 0.0f, s2 = 0.0f;
    for (int c = threadIdx.x; c < L; c += 256) {
        float v = z[base + c];
        s += v;
        s2 += v * v;
    }
    for (int off = 32; off > 0; off >>= 1) {
        s += __shfl_down(s, off);
        s2 += __shfl_down(s2, off);
    }
    __shared__ float red[8];
    int wave = threadIdx.x >> 6;
    int lane = threadIdx.x & 63;
    if (lane == 0) { red[wave] = s; red[4 + wave] = s2; }
    __syncthreads();
    s  = red[0] + red[1] + red[2] + red[3];
    s2 = red[4] + red[5] + red[6] + red[7];
    float invL = 1.0f / (float)L;
    float mean = s * invL;
    float var = s2 * invL - mean * mean;
    float inv = rsqrtf(var + 1e-5f);
    for (int c = threadIdx.x; c < L; c += 256) {
        float v = (z[base + c] - mean) * inv * g[c] + be[c];
        if (v < 0.0f) v = 0.0f;
        out[base + c] = f2b(v);
    }
}

extern "C" void kernel_launch(void* const* d_in, const int* in_sizes, int n_in,
                              void* d_out, int out_size, void* d_ws, size_t ws_size,
                              hipStream_t stream) {
    const float* x    = (const float*)d_in[0];
    const int*   ei   = (const int*)d_in[1];
    const int*   agent= (const int*)d_in[2];
    const float* Wgcn = (const float*)d_in[3];
    const float* bgcn = (const float*)d_in[4];
    const float* W1   = (const float*)d_in[5];
    const float* b1   = (const float*)d_in[6];
    const float* g1   = (const float*)d_in[7];
    const float* be1  = (const float*)d_in[8];
    const float* W2   = (const float*)d_in[9];
    const float* b2   = (const float*)d_in[10];
    const float* g2   = (const float*)d_in[11];
    const float* be2  = (const float*)d_in[12];
    const float* Wmu  = (const float*)d_in[13];
    const float* bmu  = (const float*)d_in[14];
    float* out = (float*)d_out;

    const int* srcp = ei;
    const int* dstp = ei + N_EDGES;

    // workspace layout (256B aligned)
    char* ws = (char*)d_ws;
    size_t off = 0;
    int* deg = (int*)(ws + off);     off += ((size_t)N_NODES * 4 + 255) & ~(size_t)255;
    float* dis = (float*)(ws + off); off += ((size_t)N_NODES * 4 + 255) & ~(size_t)255;
    int* nid = (int*)(ws + off);     off += ((size_t)N_NODES * 4 + 255) & ~(size_t)255;
    int* list = (int*)(ws + off);    off += ((size_t)N_AGENTS * 4 + 255) & ~(size_t)255;
    int* cnt = (int*)(ws + off);     off += 256;
    int* rowoff = (int*)(ws + off);  off += ((size_t)(N_AGENTS + 1) * 4 + 255) & ~(size_t)255;
    int* fill = (int*)(ws + off);    off += ((size_t)N_AGENTS * 4 + 255) & ~(size_t)255;
    int* ebuf = (int*)(ws + off);    off += ((size_t)N_EDGES * 4 + 255) & ~(size_t)255;
    unsigned short* xb     = (unsigned short*)(ws + off); off += ((size_t)N_NODES * IN_DIM * 2 + 255) & ~(size_t)255;
    unsigned short* wgcn_t = (unsigned short*)(ws + off); off += ((size_t)IN_DIM * HID * 2 + 255) & ~(size_t)255;
    unsigned short* w1_t   = (unsigned short*)(ws + off); off += ((size_t)HID * FC1 * 2 + 255) & ~(size_t)255;
    unsigned short* w2_t   = (unsigned short*)(ws + off); off += ((size_t)FC1 * FC2 * 2 + 255) & ~(size_t)255;
    unsigned short* wmu_t  = (unsigned short*)(ws + off); off += ((size_t)FC2 * N_ACT * 2 + 255) & ~(size_t)255;
    unsigned short* xw     = (unsigned short*)(ws + off); off += ((size_t)N_NODES * HID * 2 + 255) & ~(size_t)255;
    unsigned short* h_node = (unsigned short*)(ws + off); off += ((size_t)N_AGENTS * HID * 2 + 255) & ~(size_t)255;
    unsigned short* h0 = (unsigned short*)(ws + off);     off += ((size_t)N_AGENTS * HID * 2 + 255) & ~(size_t)255;
    float* z = (float*)(ws + off);   off += ((size_t)N_AGENTS * FC1 * 4 + 255) & ~(size_t)255;
    unsigned short* h1 = (unsigned short*)(ws + off);     off += ((size_t)N_AGENTS * FC1 * 2 + 255) & ~(size_t)255;
    unsigned short* h2 = (unsigned short*)(ws + off);     off += ((size_t)N_AGENTS * FC2 * 2 + 255) & ~(size_t)255;

    // ---- graph prep / CSR build ----
    init_k<<<(N_NODES + 255) / 256, 256, 0, stream>>>(deg, nid, fill, cnt);
    claim_k<<<(N_AGENTS + 255) / 256, 256, 0, stream>>>(agent, nid);
    compact_k<<<(N_NODES + 255) / 256, 256, 0, stream>>>(nid, list, cnt);
    degree_k<<<(N_EDGES + 255) / 256, 256, 0, stream>>>(dstp, deg);
    dis_k<<<(N_NODES + 255) / 256, 256, 0, stream>>>(deg, dis);
    scan_k<<<1, 256, 0, stream>>>(deg, list, cnt, rowoff);
    fill_k<<<(N_EDGES + 255) / 256, 256, 0, stream>>>(srcp, dstp, nid, rowoff, fill, ebuf);

    // ---- dtype prep ----
    cvt_k<<<(N_NODES * IN_DIM + 255) / 256, 256, 0, stream>>>(x, xb, N_NODES * IN_DIM);
    tcvt_k<<<(IN_DIM * HID + 255) / 256, 256, 0, stream>>>(Wgcn, wgcn_t, IN_DIM, HID);
    tcvt_k<<<(HID * FC1 + 255) / 256, 256, 0, stream>>>(W1, w1_t, HID, FC1);
    tcvt_k<<<(FC1 * FC2 + 255) / 256, 256, 0, stream>>>(W2, w2_t, FC1, FC2);
    tcvt_k<<<(FC2 * N_ACT + 255) / 256, 256, 0, stream>>>(Wmu, wmu_t, FC2, N_ACT);

    // xw = x @ W_gcn   [50000,128] @ [128,256] -> bf16
    {
        int tiles = (N_NODES / 16) * (HID / 16);
        gemm_k<<<(tiles + 3) / 4, 256, 0, stream>>>(xb, wgcn_t, (const float*)0,
                                                    xw, (float*)0, N_NODES, HID, IN_DIM, 0);
    }

    // per-needed-node aggregation (register accumulate, no f32 atomics)
    accum_k<<<N_AGENTS, 256, 0, stream>>>(cnt, list, rowoff, ebuf, dis, xw, bgcn, h_node);

    // per-agent gather
    gather_k<<<N_AGENTS, 256, 0, stream>>>(agent, nid, h_node, h0);

    // FC1 -> LN+relu
    {
        int tiles = (N_AGENTS / 16) * (FC1 / 16);
        gemm_k<<<(tiles + 3) / 4, 256, 0, stream>>>(h0, w1_t, b1, (unsigned short*)0, z,
                                                    N_AGENTS, FC1, HID, 1);
        ln_relu_k<<<N_AGENTS, 256, 0, stream>>>(z, g1, be1, h1, FC1);
    }

    // FC2 -> LN+relu
    {
        int tiles = (N_AGENTS / 16) * (FC2 / 16);
        gemm_k<<<(tiles + 3) / 4, 256, 0, stream>>>(h1, w2_t, b2, (unsigned short*)0, z,
                                                    N_AGENTS, FC2, FC1, 1);
        ln_relu_k<<<N_AGENTS, 256, 0, stream>>>(z, g2, be2, h2, FC2);
    }

    // head: sigmoid(h2 @ Wmu + bmu) -> f32 out
    {
        int tiles = (N_AGENTS / 16) * (N_ACT / 16);
        gemm_k<<<(tiles + 3) / 4, 256, 0, stream>>>(h2, wmu_t, bmu, (unsigned short*)0, out,
                                                    N_AGENTS, N_ACT, FC2, 2);
    }
}

// Round 5
// 345.803 us; speedup vs baseline: 2.4351x; 1.4747x over previous
//
#include <hip/hip_runtime.h>
#include <hip/hip_bf16.h>
#include <math.h>

#define N_NODES  50000
#define N_EDGES  800000
#define IN_DIM   128
#define HID      256
#define FC1      1024
#define FC2      512
#define N_ACT    16
#define N_AGENTS 8192

#define BM 128
#define BN 128
#define BK 32
#define LDK 40   // padded LDS leading dim: 16B-aligned rows, ~2-way bank aliasing

typedef short bf16x8 __attribute__((ext_vector_type(8)));
typedef float floatx4 __attribute__((ext_vector_type(4)));

__device__ __forceinline__ unsigned short f2b(float f) {
    union { float f; unsigned int i; } v;
    v.f = f;
    unsigned int lsb = (v.i >> 16) & 1u;
    v.i += 0x7fffu + lsb;            // round-to-nearest-even
    return (unsigned short)(v.i >> 16);
}

__device__ __forceinline__ float b2f(unsigned short u) {
    union { unsigned int i; float f; } v;
    v.i = ((unsigned int)u) << 16;
    return v.f;
}

// ---- init: deg=0, mark=-1, fill=0, cnt=0 ----
__global__ __launch_bounds__(256) void init_k(int* deg, int* nid, int* fill, int* cnt) {
    int i = blockIdx.x * 256 + threadIdx.x;
    if (i < N_NODES) { deg[i] = 0; nid[i] = -1; }
    if (i < N_AGENTS) fill[i] = 0;
    if (i == 0) *cnt = 0;
}

// ---- claim: mark nodes referenced by any agent ----
__global__ __launch_bounds__(256) void claim_k(const int* agent_idx, int* nid) {
    int i = blockIdx.x * 256 + threadIdx.x;
    if (i < N_AGENTS) {
        int n = agent_idx[i];
        atomicCAS(&nid[n], -1, i);
    }
}

// ---- compact: assign compact ids to marked nodes ----
__global__ __launch_bounds__(256) void compact_k(int* nid, int* list, int* cnt) {
    int i = blockIdx.x * 256 + threadIdx.x;
    if (i < N_NODES) {
        if (nid[i] != -1) {
            int c = atomicAdd(cnt, 1);
            nid[i] = c;
            list[c] = i;
        }
    }
}

// ---- in-degree over real edges (int atomics) ----
__global__ __launch_bounds__(256) void degree_k(const int* dst, int* deg) {
    int e = blockIdx.x * 256 + threadIdx.x;
    if (e < N_EDGES) atomicAdd(&deg[dst[e]], 1);
}

// ---- dis = rsqrt(deg + 1)  (self-loop included) ----
__global__ __launch_bounds__(256) void dis_k(const int* deg, float* dis) {
    int i = blockIdx.x * 256 + threadIdx.x;
    if (i < N_NODES) dis[i] = rsqrtf((float)(deg[i] + 1));
}

// ---- exclusive scan of row lengths (deg[list[c]]) over cnt rows, 1 block ----
__global__ __launch_bounds__(256) void scan_k(const int* deg, const int* list,
                                              const int* cntp, int* rowoff) {
    __shared__ int buf[256];
    __shared__ int base_s;
    int n = *cntp;
    int tid = threadIdx.x;
    if (tid == 0) base_s = 0;
    __syncthreads();
    for (int start = 0; start < n; start += 256) {
        int c = start + tid;
        int v = (c < n) ? deg[list[c]] : 0;
        buf[tid] = v;
        __syncthreads();
        for (int o = 1; o < 256; o <<= 1) {
            int t = (tid >= o) ? buf[tid - o] : 0;
            __syncthreads();
            buf[tid] += t;
            __syncthreads();
        }
        int incl = buf[tid];
        int base = base_s;
        if (c < n) rowoff[c] = base + incl - v;     // exclusive
        __syncthreads();
        if (tid == 255) base_s = base + incl;
        __syncthreads();
    }
    if (tid == 0) rowoff[n] = base_s;
}

// ---- fill buckets: for needed dsts, append src to its row ----
__global__ __launch_bounds__(256) void fill_k(const int* __restrict__ src,
                                              const int* __restrict__ dst,
                                              const int* __restrict__ nid,
                                              const int* __restrict__ rowoff,
                                              int* __restrict__ fill,
                                              int* __restrict__ ebuf) {
    int e = blockIdx.x * 256 + threadIdx.x;
    if (e >= N_EDGES) return;
    int c = nid[dst[e]];
    if (c < 0) return;
    int p = atomicAdd(&fill[c], 1);
    ebuf[rowoff[c] + p] = src[e];
}

// ---- accumulate per needed node: sum in-edges + self-loop + bias, relu -> bf16 ----
__global__ __launch_bounds__(256) void accum_k(const int* __restrict__ cntp,
                                               const int* __restrict__ list,
                                               const int* __restrict__ rowoff,
                                               const int* __restrict__ ebuf,
                                               const float* __restrict__ dis,
                                               const unsigned short* __restrict__ xw,
                                               const float* __restrict__ bgcn,
                                               unsigned short* __restrict__ h_node) {
    int c = blockIdx.x;
    if (c >= *cntp) return;
    int n = list[c];
    int lane = threadIdx.x & 63;
    int wave = threadIdx.x >> 6;
    int beg = rowoff[c], end = rowoff[c + 1];
    float dn = dis[n];
    floatx4 acc = {0.0f, 0.0f, 0.0f, 0.0f};
    for (int i = beg + wave; i < end; i += 4) {
        int s = ebuf[i];
        float w = dis[s] * dn;
        ushort4 u = *(const ushort4*)(xw + (size_t)s * HID + lane * 4);
        acc.x += w * b2f(u.x);
        acc.y += w * b2f(u.y);
        acc.z += w * b2f(u.z);
        acc.w += w * b2f(u.w);
    }
    __shared__ float part[4][HID];
    part[wave][lane * 4 + 0] = acc.x;
    part[wave][lane * 4 + 1] = acc.y;
    part[wave][lane * 4 + 2] = acc.z;
    part[wave][lane * 4 + 3] = acc.w;
    __syncthreads();
    int t = threadIdx.x;   // channel 0..255
    float v = part[0][t] + part[1][t] + part[2][t] + part[3][t];
    v += b2f(xw[(size_t)n * HID + t]) * dn * dn + bgcn[t];
    if (v < 0.0f) v = 0.0f;
    h_node[(size_t)c * HID + t] = f2b(v);
}

// ---- gather per agent: copy its node's bf16 row ----
__global__ __launch_bounds__(256) void gather_k(const int* __restrict__ agent_idx,
                                                const int* __restrict__ nid,
                                                const unsigned short* __restrict__ h_node,
                                                unsigned short* __restrict__ h0) {
    int a = blockIdx.x;
    int t = threadIdx.x;
    int c = nid[agent_idx[a]];
    h0[(size_t)a * HID + t] = h_node[(size_t)c * HID + t];
}

// ---- convert f32 -> bf16 (for x), 4 elems/thread ----
__global__ __launch_bounds__(256) void cvt_k(const float* __restrict__ in,
                                             unsigned short* __restrict__ out, int n4) {
    int i = blockIdx.x * 256 + threadIdx.x;
    if (i < n4) {
        float4 v = ((const float4*)in)[i];
        ushort4 o;
        o.x = f2b(v.x); o.y = f2b(v.y); o.z = f2b(v.z); o.w = f2b(v.w);
        ((ushort4*)out)[i] = o;
    }
}

// ---- transpose + convert: f32 [K,N] -> bf16 [N,K] ----
__global__ __launch_bounds__(256) void tcvt_k(const float* in, unsigned short* out,
                                              int K, int N) {
    int i = blockIdx.x * 256 + threadIdx.x;
    if (i < K * N) {
        int k = i / N;
        int n = i - k * N;
        out[n * K + k] = f2b(in[i]);
    }
}

// ---- simple GEMM (kept for the tiny head): one wave per 16x16 tile ----
// mode 2: store f32 sigmoid(v + bias) to outf
__global__ __launch_bounds__(256) void gemm_k(const unsigned short* __restrict__ A,
                                              const unsigned short* __restrict__ Bt,
                                              const float* __restrict__ bias,
                                              unsigned short* __restrict__ outb,
                                              float* __restrict__ outf,
                                              int M, int N, int K, int mode) {
    int wave = threadIdx.x >> 6;
    int lane = threadIdx.x & 63;
    int tiles_n = N >> 4;
    int tiles = (M >> 4) * tiles_n;
    int tile = blockIdx.x * 4 + wave;
    if (tile >= tiles) return;
    int tm = tile / tiles_n;
    int tn = tile - tm * tiles_n;
    int r16 = lane & 15;
    int quad = lane >> 4;
    const bf16x8* pa = (const bf16x8*)(A + (size_t)(tm * 16 + r16) * K + quad * 8);
    const bf16x8* pb = (const bf16x8*)(Bt + (size_t)(tn * 16 + r16) * K + quad * 8);
    floatx4 acc = {0.0f, 0.0f, 0.0f, 0.0f};
    int ksteps = K >> 5;
    for (int s = 0; s < ksteps; ++s) {
        bf16x8 a = pa[4 * s];
        bf16x8 b = pb[4 * s];
        acc = __builtin_amdgcn_mfma_f32_16x16x32_bf16(a, b, acc, 0, 0, 0);
    }
    int ocol = tn * 16 + r16;
    float bv = 0.0f;
    if (mode != 0) bv = bias[ocol];
    for (int r = 0; r < 4; ++r) {
        int orow = tm * 16 + quad * 4 + r;
        size_t idx = (size_t)orow * N + ocol;
        float v = acc[r];
        if (mode == 0) {
            outb[idx] = f2b(v);
        } else if (mode == 1) {
            outf[idx] = v + bv;
        } else {
            v += bv;
            outf[idx] = 1.0f / (1.0f + expf(-v));
        }
    }
}

// ---- tiled GEMM: C[M,N] = A[M,K] @ Bt[N,K]^T ----
// 128x128 block tile, BK=32, 4 waves each 64x64 (4x4 MFMA), reg-prefetch pipeline.
// mode 0: C -> bf16 (outb);  mode 1: C+bias -> f32 (outf)
// Requires: N % 128 == 0, K % 32 == 0. M arbitrary (row-clamped loads, guarded stores).
__global__ __launch_bounds__(256) void gemm_tiled_k(const unsigned short* __restrict__ A,
                                                    const unsigned short* __restrict__ Bt,
                                                    const float* __restrict__ bias,
                                                    unsigned short* __restrict__ outb,
                                                    float* __restrict__ outf,
                                                    int M, int N, int K, int mode) {
    __shared__ unsigned short As[BM][LDK];
    __shared__ unsigned short Bs[BN][LDK];

    int tn = blockIdx.x;        // N / 128 tiles
    int tm = blockIdx.y;        // ceil(M / 128) tiles
    int tid = threadIdx.x;
    int lane = tid & 63;
    int wave = tid >> 6;
    int wm = wave >> 1, wn = wave & 1;
    int r16 = lane & 15, quad = lane >> 4;

    // staging map: thread t loads rows {t/4, t/4+64}, col (t%4)*8 (8 bf16 = 16B)
    int srow = tid >> 2;
    int scol = (tid & 3) * 8;
    int ar0 = tm * BM + srow;        if (ar0 > M - 1) ar0 = M - 1;
    int ar1 = tm * BM + srow + 64;   if (ar1 > M - 1) ar1 = M - 1;
    int br0 = tn * BN + srow;
    int br1 = tn * BN + srow + 64;
    const unsigned short* pa0 = A + (size_t)ar0 * K + scol;
    const unsigned short* pa1 = A + (size_t)ar1 * K + scol;
    const unsigned short* pb0 = Bt + (size_t)br0 * K + scol;
    const unsigned short* pb1 = Bt + (size_t)br1 * K + scol;

    floatx4 acc[4][4];
    #pragma unroll
    for (int i = 0; i < 4; ++i)
        #pragma unroll
        for (int j = 0; j < 4; ++j)
            acc[i][j] = (floatx4){0.0f, 0.0f, 0.0f, 0.0f};

    bf16x8 ra0 = *(const bf16x8*)pa0;
    bf16x8 ra1 = *(const bf16x8*)pa1;
    bf16x8 rb0 = *(const bf16x8*)pb0;
    bf16x8 rb1 = *(const bf16x8*)pb1;

    for (int k0 = 0; k0 < K; k0 += BK) {
        *(bf16x8*)&As[srow][scol]      = ra0;
        *(bf16x8*)&As[srow + 64][scol] = ra1;
        *(bf16x8*)&Bs[srow][scol]      = rb0;
        *(bf16x8*)&Bs[srow + 64][scol] = rb1;
        __syncthreads();

        if (k0 + BK < K) {               // prefetch next K-slab (overlaps MFMA)
            ra0 = *(const bf16x8*)(pa0 + k0 + BK);
            ra1 = *(const bf16x8*)(pa1 + k0 + BK);
            rb0 = *(const bf16x8*)(pb0 + k0 + BK);
            rb1 = *(const bf16x8*)(pb1 + k0 + BK);
        }

        bf16x8 af[4], bfr[4];
        #pragma unroll
        for (int i = 0; i < 4; ++i)
            af[i] = *(const bf16x8*)&As[wm * 64 + i * 16 + r16][quad * 8];
        #pragma unroll
        for (int j = 0; j < 4; ++j)
            bfr[j] = *(const bf16x8*)&Bs[wn * 64 + j * 16 + r16][quad * 8];
        #pragma unroll
        for (int i = 0; i < 4; ++i)
            #pragma unroll
            for (int j = 0; j < 4; ++j)
                acc[i][j] = __builtin_amdgcn_mfma_f32_16x16x32_bf16(af[i], bfr[j], acc[i][j], 0, 0, 0);
        __syncthreads();
    }

    // epilogue: C/D layout col = lane&15, row = quad*4 + r
    #pragma unroll
    for (int j = 0; j < 4; ++j) {
        int ocol = tn * BN + wn * 64 + j * 16 + r16;
        float bv = (mode != 0) ? bias[ocol] : 0.0f;
        #pragma unroll
        for (int i = 0; i < 4; ++i) {
            int orow_base = tm * BM + wm * 64 + i * 16 + quad * 4;
            #pragma unroll
            for (int r = 0; r < 4; ++r) {
                int orow = orow_base + r;
                if (orow < M) {
                    size_t idx = (size_t)orow * N + ocol;
                    float v = acc[i][j][r];
                    if (mode == 0) outb[idx] = f2b(v);
                    else           outf[idx] = v + bv;
                }
            }
        }
    }
}

// ---- single-pass row LayerNorm (+affine) + relu, f32 in -> bf16 out ----
// L/256 <= 4 values cached in registers; z read exactly once.
__global__ __launch_bounds__(256) void ln_relu_k(const float* __restrict__ z,
                                                 const float* __restrict__ g,
                                                 const float* __restrict__ be,
                                                 unsigned short* __restrict__ out, int L) {
    size_t base = (size_t)blockIdx.x * L;
    int nc = L >> 8;                 // 4 (FC1) or 2 (FC2)
    float vreg[4];
    float s = 0.0f, s2 = 0.0f;
    for (int i = 0; i < nc; ++i) {
        float v = z[base + i * 256 + threadIdx.x];
        vreg[i] = v;
        s += v;
        s2 += v * v;
    }
    for (int off = 32; off > 0; off >>= 1) {
        s += __shfl_down(s, off);
        s2 += __shfl_down(s2, off);
    }
    __shared__ float red[8];
    int wave = threadIdx.x >> 6;
    int lane = threadIdx.x & 63;
    if (lane == 0) { red[wave] = s; red[4 + wave] = s2; }
    __syncthreads();
    s  = red[0] + red[1] + red[2] + red[3];
    s2 = red[4] + red[5] + red[6] + red[7];
    float invL = 1.0f / (float)L;
    float mean = s * invL;
    float var = s2 * invL - mean * mean;
    float inv = rsqrtf(var + 1e-5f);
    for (int i = 0; i < nc; ++i) {
        int c = i * 256 + threadIdx.x;
        float v = (vreg[i] - mean) * inv * g[c] + be[c];
        if (v < 0.0f) v = 0.0f;
        out[base + c] = f2b(v);
    }
}

extern "C" void kernel_launch(void* const* d_in, const int* in_sizes, int n_in,
                              void* d_out, int out_size, void* d_ws, size_t ws_size,
                              hipStream_t stream) {
    const float* x    = (const float*)d_in[0];
    const int*   ei   = (const int*)d_in[1];
    const int*   agent= (const int*)d_in[2];
    const float* Wgcn = (const float*)d_in[3];
    const float* bgcn = (const float*)d_in[4];
    const float* W1   = (const float*)d_in[5];
    const float* b1   = (const float*)d_in[6];
    const float* g1   = (const float*)d_in[7];
    const float* be1  = (const float*)d_in[8];
    const float* W2   = (const float*)d_in[9];
    const float* b2   = (const float*)d_in[10];
    const float* g2   = (const float*)d_in[11];
    const float* be2  = (const float*)d_in[12];
    const float* Wmu  = (const float*)d_in[13];
    const float* bmu  = (const float*)d_in[14];
    float* out = (float*)d_out;

    const int* srcp = ei;
    const int* dstp = ei + N_EDGES;

    // workspace layout (256B aligned)
    char* ws = (char*)d_ws;
    size_t off = 0;
    int* deg = (int*)(ws + off);     off += ((size_t)N_NODES * 4 + 255) & ~(size_t)255;
    float* dis = (float*)(ws + off); off += ((size_t)N_NODES * 4 + 255) & ~(size_t)255;
    int* nid = (int*)(ws + off);     off += ((size_t)N_NODES * 4 + 255) & ~(size_t)255;
    int* list = (int*)(ws + off);    off += ((size_t)N_AGENTS * 4 + 255) & ~(size_t)255;
    int* cnt = (int*)(ws + off);     off += 256;
    int* rowoff = (int*)(ws + off);  off += ((size_t)(N_AGENTS + 1) * 4 + 255) & ~(size_t)255;
    int* fill = (int*)(ws + off);    off += ((size_t)N_AGENTS * 4 + 255) & ~(size_t)255;
    int* ebuf = (int*)(ws + off);    off += ((size_t)N_EDGES * 4 + 255) & ~(size_t)255;
    unsigned short* xb     = (unsigned short*)(ws + off); off += ((size_t)N_NODES * IN_DIM * 2 + 255) & ~(size_t)255;
    unsigned short* wgcn_t = (unsigned short*)(ws + off); off += ((size_t)IN_DIM * HID * 2 + 255) & ~(size_t)255;
    unsigned short* w1_t   = (unsigned short*)(ws + off); off += ((size_t)HID * FC1 * 2 + 255) & ~(size_t)255;
    unsigned short* w2_t   = (unsigned short*)(ws + off); off += ((size_t)FC1 * FC2 * 2 + 255) & ~(size_t)255;
    unsigned short* wmu_t  = (unsigned short*)(ws + off); off += ((size_t)FC2 * N_ACT * 2 + 255) & ~(size_t)255;
    unsigned short* xw     = (unsigned short*)(ws + off); off += ((size_t)N_NODES * HID * 2 + 255) & ~(size_t)255;
    unsigned short* h_node = (unsigned short*)(ws + off); off += ((size_t)N_AGENTS * HID * 2 + 255) & ~(size_t)255;
    unsigned short* h0 = (unsigned short*)(ws + off);     off += ((size_t)N_AGENTS * HID * 2 + 255) & ~(size_t)255;
    float* z = (float*)(ws + off);   off += ((size_t)N_AGENTS * FC1 * 4 + 255) & ~(size_t)255;
    unsigned short* h1 = (unsigned short*)(ws + off);     off += ((size_t)N_AGENTS * FC1 * 2 + 255) & ~(size_t)255;
    unsigned short* h2 = (unsigned short*)(ws + off);     off += ((size_t)N_AGENTS * FC2 * 2 + 255) & ~(size_t)255;

    // ---- graph prep / CSR build ----
    init_k<<<(N_NODES + 255) / 256, 256, 0, stream>>>(deg, nid, fill, cnt);
    claim_k<<<(N_AGENTS + 255) / 256, 256, 0, stream>>>(agent, nid);
    compact_k<<<(N_NODES + 255) / 256, 256, 0, stream>>>(nid, list, cnt);
    degree_k<<<(N_EDGES + 255) / 256, 256, 0, stream>>>(dstp, deg);
    dis_k<<<(N_NODES + 255) / 256, 256, 0, stream>>>(deg, dis);
    scan_k<<<1, 256, 0, stream>>>(deg, list, cnt, rowoff);
    fill_k<<<(N_EDGES + 255) / 256, 256, 0, stream>>>(srcp, dstp, nid, rowoff, fill, ebuf);

    // ---- dtype prep ----
    cvt_k<<<(N_NODES * IN_DIM / 4 + 255) / 256, 256, 0, stream>>>(x, xb, N_NODES * IN_DIM / 4);
    tcvt_k<<<(IN_DIM * HID + 255) / 256, 256, 0, stream>>>(Wgcn, wgcn_t, IN_DIM, HID);
    tcvt_k<<<(HID * FC1 + 255) / 256, 256, 0, stream>>>(W1, w1_t, HID, FC1);
    tcvt_k<<<(FC1 * FC2 + 255) / 256, 256, 0, stream>>>(W2, w2_t, FC1, FC2);
    tcvt_k<<<(FC2 * N_ACT + 255) / 256, 256, 0, stream>>>(Wmu, wmu_t, FC2, N_ACT);

    // xw = x @ W_gcn   [50000,128] @ [128,256] -> bf16
    {
        dim3 grid(HID / BN, (N_NODES + BM - 1) / BM);
        gemm_tiled_k<<<grid, 256, 0, stream>>>(xb, wgcn_t, (const float*)0,
                                               xw, (float*)0, N_NODES, HID, IN_DIM, 0);
    }

    // per-needed-node aggregation (register accumulate, no f32 atomics)
    accum_k<<<N_AGENTS, 256, 0, stream>>>(cnt, list, rowoff, ebuf, dis, xw, bgcn, h_node);

    // per-agent gather
    gather_k<<<N_AGENTS, 256, 0, stream>>>(agent, nid, h_node, h0);

    // FC1 -> LN+relu
    {
        dim3 grid(FC1 / BN, N_AGENTS / BM);
        gemm_tiled_k<<<grid, 256, 0, stream>>>(h0, w1_t, b1, (unsigned short*)0, z,
                                               N_AGENTS, FC1, HID, 1);
        ln_relu_k<<<N_AGENTS, 256, 0, stream>>>(z, g1, be1, h1, FC1);
    }

    // FC2 -> LN+relu
    {
        dim3 grid(FC2 / BN, N_AGENTS / BM);
        gemm_tiled_k<<<grid, 256, 0, stream>>>(h1, w2_t, b2, (unsigned short*)0, z,
                                               N_AGENTS, FC2, FC1, 1);
        ln_relu_k<<<N_AGENTS, 256, 0, stream>>>(z, g2, be2, h2, FC2);
    }

    // head: sigmoid(h2 @ Wmu + bmu) -> f32 out
    {
        int tiles = (N_AGENTS / 16) * (N_ACT / 16);
        gemm_k<<<(tiles + 3) / 4, 256, 0, stream>>>(h2, wmu_t, bmu, (unsigned short*)0, out,
                                                    N_AGENTS, N_ACT, FC2, 2);
    }
}

// Round 6
// 308.745 us; speedup vs baseline: 2.7274x; 1.1200x over previous
//
#include <hip/hip_runtime.h>
#include <hip/hip_bf16.h>
#include <math.h>

#define N_NODES  50000
#define N_EDGES  800000
#define IN_DIM   128
#define HID      256
#define FC1      1024
#define FC2      512
#define N_ACT    16
#define N_AGENTS 8192

#define BM 128
#define BN 128
#define BK 32
#define LDK 40   // padded LDS leading dim: 16B-aligned rows, ~2-way bank aliasing

typedef short bf16x8 __attribute__((ext_vector_type(8)));
typedef float floatx4 __attribute__((ext_vector_type(4)));

__device__ __forceinline__ unsigned short f2b(float f) {
    union { float f; unsigned int i; } v;
    v.f = f;
    unsigned int lsb = (v.i >> 16) & 1u;
    v.i += 0x7fffu + lsb;            // round-to-nearest-even
    return (unsigned short)(v.i >> 16);
}

__device__ __forceinline__ float b2f(unsigned short u) {
    union { unsigned int i; float f; } v;
    v.i = ((unsigned int)u) << 16;
    return v.f;
}

// ---- init: deg=0, mark=-1, fill=0, cnt=0, etot=0 ----
__global__ __launch_bounds__(256) void init_k(int* deg, int* nid, int* fill,
                                              int* cnt, int* etot) {
    int i = blockIdx.x * 256 + threadIdx.x;
    if (i < N_NODES) { deg[i] = 0; nid[i] = -1; }
    if (i < N_AGENTS) fill[i] = 0;
    if (i == 0) { *cnt = 0; *etot = 0; }
}

// ---- claim: mark nodes referenced by any agent ----
__global__ __launch_bounds__(256) void claim_k(const int* agent_idx, int* nid) {
    int i = blockIdx.x * 256 + threadIdx.x;
    if (i < N_AGENTS) {
        int n = agent_idx[i];
        atomicCAS(&nid[n], -1, i);
    }
}

// ---- in-degree over real edges (int atomics) ----
__global__ __launch_bounds__(256) void degree_k(const int* dst, int* deg) {
    int e = blockIdx.x * 256 + threadIdx.x;
    if (e < N_EDGES) atomicAdd(&deg[dst[e]], 1);
}

// ---- compact + row allocation: compact ids AND atomic bump-alloc row bases ----
// (CSR row order is irrelevant; row length == deg[n] since every in-edge of a
//  needed node passes fill_k's filter. This replaces the 43us serial scan_k.)
__global__ __launch_bounds__(256) void compact_k(int* nid, int* list, int* cnt,
                                                 const int* deg, int* rowbeg, int* etot) {
    int i = blockIdx.x * 256 + threadIdx.x;
    if (i < N_NODES) {
        if (nid[i] != -1) {
            int c = atomicAdd(cnt, 1);
            nid[i] = c;
            list[c] = i;
            rowbeg[c] = atomicAdd(etot, deg[i]);
        }
    }
}

// ---- dis = rsqrt(deg + 1)  (self-loop included) ----
__global__ __launch_bounds__(256) void dis_k(const int* deg, float* dis) {
    int i = blockIdx.x * 256 + threadIdx.x;
    if (i < N_NODES) dis[i] = rsqrtf((float)(deg[i] + 1));
}

// ---- fill buckets: for needed dsts, append src to its row ----
__global__ __launch_bounds__(256) void fill_k(const int* __restrict__ src,
                                              const int* __restrict__ dst,
                                              const int* __restrict__ nid,
                                              const int* __restrict__ rowbeg,
                                              int* __restrict__ fill,
                                              int* __restrict__ ebuf) {
    int e = blockIdx.x * 256 + threadIdx.x;
    if (e >= N_EDGES) return;
    int c = nid[dst[e]];
    if (c < 0) return;
    int p = atomicAdd(&fill[c], 1);
    ebuf[rowbeg[c] + p] = src[e];
}

// ---- accumulate per needed node: sum in-edges + self-loop + bias, relu -> bf16 ----
__global__ __launch_bounds__(256) void accum_k(const int* __restrict__ cntp,
                                               const int* __restrict__ list,
                                               const int* __restrict__ rowbeg,
                                               const int* __restrict__ deg,
                                               const int* __restrict__ ebuf,
                                               const float* __restrict__ dis,
                                               const unsigned short* __restrict__ xw,
                                               const float* __restrict__ bgcn,
                                               unsigned short* __restrict__ h_node) {
    int c = blockIdx.x;
    if (c >= *cntp) return;
    int n = list[c];
    int lane = threadIdx.x & 63;
    int wave = threadIdx.x >> 6;
    int beg = rowbeg[c];
    int end = beg + deg[n];
    float dn = dis[n];
    floatx4 acc = {0.0f, 0.0f, 0.0f, 0.0f};
    for (int i = beg + wave; i < end; i += 4) {
        int s = ebuf[i];
        float w = dis[s] * dn;
        ushort4 u = *(const ushort4*)(xw + (size_t)s * HID + lane * 4);
        acc.x += w * b2f(u.x);
        acc.y += w * b2f(u.y);
        acc.z += w * b2f(u.z);
        acc.w += w * b2f(u.w);
    }
    __shared__ float part[4][HID];
    part[wave][lane * 4 + 0] = acc.x;
    part[wave][lane * 4 + 1] = acc.y;
    part[wave][lane * 4 + 2] = acc.z;
    part[wave][lane * 4 + 3] = acc.w;
    __syncthreads();
    int t = threadIdx.x;   // channel 0..255
    float v = part[0][t] + part[1][t] + part[2][t] + part[3][t];
    v += b2f(xw[(size_t)n * HID + t]) * dn * dn + bgcn[t];
    if (v < 0.0f) v = 0.0f;
    h_node[(size_t)c * HID + t] = f2b(v);
}

// ---- gather per agent: copy its node's bf16 row ----
__global__ __launch_bounds__(256) void gather_k(const int* __restrict__ agent_idx,
                                                const int* __restrict__ nid,
                                                const unsigned short* __restrict__ h_node,
                                                unsigned short* __restrict__ h0) {
    int a = blockIdx.x;
    int t = threadIdx.x;
    int c = nid[agent_idx[a]];
    h0[(size_t)a * HID + t] = h_node[(size_t)c * HID + t];
}

// ---- convert f32 -> bf16 (for x), 4 elems/thread ----
__global__ __launch_bounds__(256) void cvt_k(const float* __restrict__ in,
                                             unsigned short* __restrict__ out, int n4) {
    int i = blockIdx.x * 256 + threadIdx.x;
    if (i < n4) {
        float4 v = ((const float4*)in)[i];
        ushort4 o;
        o.x = f2b(v.x); o.y = f2b(v.y); o.z = f2b(v.z); o.w = f2b(v.w);
        ((ushort4*)out)[i] = o;
    }
}

// ---- transpose + convert: f32 [K,N] -> bf16 [N,K] ----
__global__ __launch_bounds__(256) void tcvt_k(const float* in, unsigned short* out,
                                              int K, int N) {
    int i = blockIdx.x * 256 + threadIdx.x;
    if (i < K * N) {
        int k = i / N;
        int n = i - k * N;
        out[n * K + k] = f2b(in[i]);
    }
}

// ---- simple GEMM (kept for the tiny head): one wave per 16x16 tile ----
// mode 2: store f32 sigmoid(v + bias) to outf
__global__ __launch_bounds__(256) void gemm_k(const unsigned short* __restrict__ A,
                                              const unsigned short* __restrict__ Bt,
                                              const float* __restrict__ bias,
                                              unsigned short* __restrict__ outb,
                                              float* __restrict__ outf,
                                              int M, int N, int K, int mode) {
    int wave = threadIdx.x >> 6;
    int lane = threadIdx.x & 63;
    int tiles_n = N >> 4;
    int tiles = (M >> 4) * tiles_n;
    int tile = blockIdx.x * 4 + wave;
    if (tile >= tiles) return;
    int tm = tile / tiles_n;
    int tn = tile - tm * tiles_n;
    int r16 = lane & 15;
    int quad = lane >> 4;
    const bf16x8* pa = (const bf16x8*)(A + (size_t)(tm * 16 + r16) * K + quad * 8);
    const bf16x8* pb = (const bf16x8*)(Bt + (size_t)(tn * 16 + r16) * K + quad * 8);
    floatx4 acc = {0.0f, 0.0f, 0.0f, 0.0f};
    int ksteps = K >> 5;
    for (int s = 0; s < ksteps; ++s) {
        bf16x8 a = pa[4 * s];
        bf16x8 b = pb[4 * s];
        acc = __builtin_amdgcn_mfma_f32_16x16x32_bf16(a, b, acc, 0, 0, 0);
    }
    int ocol = tn * 16 + r16;
    float bv = 0.0f;
    if (mode != 0) bv = bias[ocol];
    for (int r = 0; r < 4; ++r) {
        int orow = tm * 16 + quad * 4 + r;
        size_t idx = (size_t)orow * N + ocol;
        float v = acc[r];
        if (mode == 0) {
            outb[idx] = f2b(v);
        } else if (mode == 1) {
            outf[idx] = v + bv;
        } else {
            v += bv;
            outf[idx] = 1.0f / (1.0f + expf(-v));
        }
    }
}

// ---- tiled GEMM: C[M,N] = A[M,K] @ Bt[N,K]^T ----
// 128x128 block tile, BK=32, 4 waves each 64x64 (4x4 MFMA), reg-prefetch pipeline.
// mode 0: C -> bf16 (outb);  mode 1: C+bias -> f32 (outf)
__global__ __launch_bounds__(256) void gemm_tiled_k(const unsigned short* __restrict__ A,
                                                    const unsigned short* __restrict__ Bt,
                                                    const float* __restrict__ bias,
                                                    unsigned short* __restrict__ outb,
                                                    float* __restrict__ outf,
                                                    int M, int N, int K, int mode) {
    __shared__ unsigned short As[BM][LDK];
    __shared__ unsigned short Bs[BN][LDK];

    int tn = blockIdx.x;        // N / 128 tiles
    int tm = blockIdx.y;        // ceil(M / 128) tiles
    int tid = threadIdx.x;
    int lane = tid & 63;
    int wave = tid >> 6;
    int wm = wave >> 1, wn = wave & 1;
    int r16 = lane & 15, quad = lane >> 4;

    int srow = tid >> 2;
    int scol = (tid & 3) * 8;
    int ar0 = tm * BM + srow;        if (ar0 > M - 1) ar0 = M - 1;
    int ar1 = tm * BM + srow + 64;   if (ar1 > M - 1) ar1 = M - 1;
    int br0 = tn * BN + srow;
    int br1 = tn * BN + srow + 64;
    const unsigned short* pa0 = A + (size_t)ar0 * K + scol;
    const unsigned short* pa1 = A + (size_t)ar1 * K + scol;
    const unsigned short* pb0 = Bt + (size_t)br0 * K + scol;
    const unsigned short* pb1 = Bt + (size_t)br1 * K + scol;

    floatx4 acc[4][4];
    #pragma unroll
    for (int i = 0; i < 4; ++i)
        #pragma unroll
        for (int j = 0; j < 4; ++j)
            acc[i][j] = (floatx4){0.0f, 0.0f, 0.0f, 0.0f};

    bf16x8 ra0 = *(const bf16x8*)pa0;
    bf16x8 ra1 = *(const bf16x8*)pa1;
    bf16x8 rb0 = *(const bf16x8*)pb0;
    bf16x8 rb1 = *(const bf16x8*)pb1;

    for (int k0 = 0; k0 < K; k0 += BK) {
        *(bf16x8*)&As[srow][scol]      = ra0;
        *(bf16x8*)&As[srow + 64][scol] = ra1;
        *(bf16x8*)&Bs[srow][scol]      = rb0;
        *(bf16x8*)&Bs[srow + 64][scol] = rb1;
        __syncthreads();

        if (k0 + BK < K) {               // prefetch next K-slab (overlaps MFMA)
            ra0 = *(const bf16x8*)(pa0 + k0 + BK);
            ra1 = *(const bf16x8*)(pa1 + k0 + BK);
            rb0 = *(const bf16x8*)(pb0 + k0 + BK);
            rb1 = *(const bf16x8*)(pb1 + k0 + BK);
        }

        bf16x8 af[4], bfr[4];
        #pragma unroll
        for (int i = 0; i < 4; ++i)
            af[i] = *(const bf16x8*)&As[wm * 64 + i * 16 + r16][quad * 8];
        #pragma unroll
        for (int j = 0; j < 4; ++j)
            bfr[j] = *(const bf16x8*)&Bs[wn * 64 + j * 16 + r16][quad * 8];
        #pragma unroll
        for (int i = 0; i < 4; ++i)
            #pragma unroll
            for (int j = 0; j < 4; ++j)
                acc[i][j] = __builtin_amdgcn_mfma_f32_16x16x32_bf16(af[i], bfr[j], acc[i][j], 0, 0, 0);
        __syncthreads();
    }

    // epilogue: C/D layout col = lane&15, row = quad*4 + r
    #pragma unroll
    for (int j = 0; j < 4; ++j) {
        int ocol = tn * BN + wn * 64 + j * 16 + r16;
        float bv = (mode != 0) ? bias[ocol] : 0.0f;
        #pragma unroll
        for (int i = 0; i < 4; ++i) {
            int orow_base = tm * BM + wm * 64 + i * 16 + quad * 4;
            #pragma unroll
            for (int r = 0; r < 4; ++r) {
                int orow = orow_base + r;
                if (orow < M) {
                    size_t idx = (size_t)orow * N + ocol;
                    float v = acc[i][j][r];
                    if (mode == 0) outb[idx] = f2b(v);
                    else           outf[idx] = v + bv;
                }
            }
        }
    }
}

// ---- single-pass row LayerNorm (+affine) + relu, f32 in -> bf16 out ----
__global__ __launch_bounds__(256) void ln_relu_k(const float* __restrict__ z,
                                                 const float* __restrict__ g,
                                                 const float* __restrict__ be,
                                                 unsigned short* __restrict__ out, int L) {
    size_t base = (size_t)blockIdx.x * L;
    int nc = L >> 8;                 // 4 (FC1) or 2 (FC2)
    float vreg[4];
    float s = 0.0f, s2 = 0.0f;
    for (int i = 0; i < nc; ++i) {
        float v = z[base + i * 256 + threadIdx.x];
        vreg[i] = v;
        s += v;
        s2 += v * v;
    }
    for (int off = 32; off > 0; off >>= 1) {
        s += __shfl_down(s, off);
        s2 += __shfl_down(s2, off);
    }
    __shared__ float red[8];
    int wave = threadIdx.x >> 6;
    int lane = threadIdx.x & 63;
    if (lane == 0) { red[wave] = s; red[4 + wave] = s2; }
    __syncthreads();
    s  = red[0] + red[1] + red[2] + red[3];
    s2 = red[4] + red[5] + red[6] + red[7];
    float invL = 1.0f / (float)L;
    float mean = s * invL;
    float var = s2 * invL - mean * mean;
    float inv = rsqrtf(var + 1e-5f);
    for (int i = 0; i < nc; ++i) {
        int c = i * 256 + threadIdx.x;
        float v = (vreg[i] - mean) * inv * g[c] + be[c];
        if (v < 0.0f) v = 0.0f;
        out[base + c] = f2b(v);
    }
}

extern "C" void kernel_launch(void* const* d_in, const int* in_sizes, int n_in,
                              void* d_out, int out_size, void* d_ws, size_t ws_size,
                              hipStream_t stream) {
    const float* x    = (const float*)d_in[0];
    const int*   ei   = (const int*)d_in[1];
    const int*   agent= (const int*)d_in[2];
    const float* Wgcn = (const float*)d_in[3];
    const float* bgcn = (const float*)d_in[4];
    const float* W1   = (const float*)d_in[5];
    const float* b1   = (const float*)d_in[6];
    const float* g1   = (const float*)d_in[7];
    const float* be1  = (const float*)d_in[8];
    const float* W2   = (const float*)d_in[9];
    const float* b2   = (const float*)d_in[10];
    const float* g2   = (const float*)d_in[11];
    const float* be2  = (const float*)d_in[12];
    const float* Wmu  = (const float*)d_in[13];
    const float* bmu  = (const float*)d_in[14];
    float* out = (float*)d_out;

    const int* srcp = ei;
    const int* dstp = ei + N_EDGES;

    // workspace layout (256B aligned)
    char* ws = (char*)d_ws;
    size_t off = 0;
    int* deg = (int*)(ws + off);     off += ((size_t)N_NODES * 4 + 255) & ~(size_t)255;
    float* dis = (float*)(ws + off); off += ((size_t)N_NODES * 4 + 255) & ~(size_t)255;
    int* nid = (int*)(ws + off);     off += ((size_t)N_NODES * 4 + 255) & ~(size_t)255;
    int* list = (int*)(ws + off);    off += ((size_t)N_AGENTS * 4 + 255) & ~(size_t)255;
    int* cnt = (int*)(ws + off);     off += 256;
    int* etot = (int*)(ws + off);    off += 256;
    int* rowbeg = (int*)(ws + off);  off += ((size_t)N_AGENTS * 4 + 255) & ~(size_t)255;
    int* fill = (int*)(ws + off);    off += ((size_t)N_AGENTS * 4 + 255) & ~(size_t)255;
    int* ebuf = (int*)(ws + off);    off += ((size_t)N_EDGES * 4 + 255) & ~(size_t)255;
    unsigned short* xb     = (unsigned short*)(ws + off); off += ((size_t)N_NODES * IN_DIM * 2 + 255) & ~(size_t)255;
    unsigned short* wgcn_t = (unsigned short*)(ws + off); off += ((size_t)IN_DIM * HID * 2 + 255) & ~(size_t)255;
    unsigned short* w1_t   = (unsigned short*)(ws + off); off += ((size_t)HID * FC1 * 2 + 255) & ~(size_t)255;
    unsigned short* w2_t   = (unsigned short*)(ws + off); off += ((size_t)FC1 * FC2 * 2 + 255) & ~(size_t)255;
    unsigned short* wmu_t  = (unsigned short*)(ws + off); off += ((size_t)FC2 * N_ACT * 2 + 255) & ~(size_t)255;
    unsigned short* xw     = (unsigned short*)(ws + off); off += ((size_t)N_NODES * HID * 2 + 255) & ~(size_t)255;
    unsigned short* h_node = (unsigned short*)(ws + off); off += ((size_t)N_AGENTS * HID * 2 + 255) & ~(size_t)255;
    unsigned short* h0 = (unsigned short*)(ws + off);     off += ((size_t)N_AGENTS * HID * 2 + 255) & ~(size_t)255;
    float* z = (float*)(ws + off);   off += ((size_t)N_AGENTS * FC1 * 4 + 255) & ~(size_t)255;
    unsigned short* h1 = (unsigned short*)(ws + off);     off += ((size_t)N_AGENTS * FC1 * 2 + 255) & ~(size_t)255;
    unsigned short* h2 = (unsigned short*)(ws + off);     off += ((size_t)N_AGENTS * FC2 * 2 + 255) & ~(size_t)255;

    // ---- graph prep / CSR build (scan-free: atomic bump allocation) ----
    init_k<<<(N_NODES + 255) / 256, 256, 0, stream>>>(deg, nid, fill, cnt, etot);
    claim_k<<<(N_AGENTS + 255) / 256, 256, 0, stream>>>(agent, nid);
    degree_k<<<(N_EDGES + 255) / 256, 256, 0, stream>>>(dstp, deg);
    compact_k<<<(N_NODES + 255) / 256, 256, 0, stream>>>(nid, list, cnt, deg, rowbeg, etot);
    dis_k<<<(N_NODES + 255) / 256, 256, 0, stream>>>(deg, dis);
    fill_k<<<(N_EDGES + 255) / 256, 256, 0, stream>>>(srcp, dstp, nid, rowbeg, fill, ebuf);

    // ---- dtype prep ----
    cvt_k<<<(N_NODES * IN_DIM / 4 + 255) / 256, 256, 0, stream>>>(x, xb, N_NODES * IN_DIM / 4);
    tcvt_k<<<(IN_DIM * HID + 255) / 256, 256, 0, stream>>>(Wgcn, wgcn_t, IN_DIM, HID);
    tcvt_k<<<(HID * FC1 + 255) / 256, 256, 0, stream>>>(W1, w1_t, HID, FC1);
    tcvt_k<<<(FC1 * FC2 + 255) / 256, 256, 0, stream>>>(W2, w2_t, FC1, FC2);
    tcvt_k<<<(FC2 * N_ACT + 255) / 256, 256, 0, stream>>>(Wmu, wmu_t, FC2, N_ACT);

    // xw = x @ W_gcn   [50000,128] @ [128,256] -> bf16
    {
        dim3 grid(HID / BN, (N_NODES + BM - 1) / BM);
        gemm_tiled_k<<<grid, 256, 0, stream>>>(xb, wgcn_t, (const float*)0,
                                               xw, (float*)0, N_NODES, HID, IN_DIM, 0);
    }

    // per-needed-node aggregation (register accumulate, no f32 atomics)
    accum_k<<<N_AGENTS, 256, 0, stream>>>(cnt, list, rowbeg, deg, ebuf, dis, xw, bgcn, h_node);

    // per-agent gather
    gather_k<<<N_AGENTS, 256, 0, stream>>>(agent, nid, h_node, h0);

    // FC1 -> LN+relu
    {
        dim3 grid(FC1 / BN, N_AGENTS / BM);
        gemm_tiled_k<<<grid, 256, 0, stream>>>(h0, w1_t, b1, (unsigned short*)0, z,
                                               N_AGENTS, FC1, HID, 1);
        ln_relu_k<<<N_AGENTS, 256, 0, stream>>>(z, g1, be1, h1, FC1);
    }

    // FC2 -> LN+relu
    {
        dim3 grid(FC2 / BN, N_AGENTS / BM);
        gemm_tiled_k<<<grid, 256, 0, stream>>>(h1, w2_t, b2, (unsigned short*)0, z,
                                               N_AGENTS, FC2, FC1, 1);
        ln_relu_k<<<N_AGENTS, 256, 0, stream>>>(z, g2, be2, h2, FC2);
    }

    // head: sigmoid(h2 @ Wmu + bmu) -> f32 out
    {
        int tiles = (N_AGENTS / 16) * (N_ACT / 16);
        gemm_k<<<(tiles + 3) / 4, 256, 0, stream>>>(h2, wmu_t, bmu, (unsigned short*)0, out,
                                                    N_AGENTS, N_ACT, FC2, 2);
    }
}

// Round 7
// 281.644 us; speedup vs baseline: 2.9898x; 1.0962x over previous
//
#include <hip/hip_runtime.h>
#include <hip/hip_bf16.h>
#include <math.h>

#define N_NODES  50000
#define N_EDGES  800000
#define IN_DIM   128
#define HID      256
#define FC1      1024
#define FC2      512
#define N_ACT    16
#define N_AGENTS 8192

#define BM 128
#define BN 128
#define BK 32
#define LDK 40   // padded LDS leading dim: 16B-aligned rows, ~2-way bank aliasing

typedef short bf16x8 __attribute__((ext_vector_type(8)));
typedef float floatx4 __attribute__((ext_vector_type(4)));

__device__ __forceinline__ unsigned short f2b(float f) {
    union { float f; unsigned int i; } v;
    v.f = f;
    unsigned int lsb = (v.i >> 16) & 1u;
    v.i += 0x7fffu + lsb;            // round-to-nearest-even
    return (unsigned short)(v.i >> 16);
}

__device__ __forceinline__ float b2f(unsigned short u) {
    union { unsigned int i; float f; } v;
    v.i = ((unsigned int)u) << 16;
    return v.f;
}

__device__ __forceinline__ bf16x8 pack8(float4 a, float4 b) {
    bf16x8 r;
    r[0] = (short)f2b(a.x); r[1] = (short)f2b(a.y);
    r[2] = (short)f2b(a.z); r[3] = (short)f2b(a.w);
    r[4] = (short)f2b(b.x); r[5] = (short)f2b(b.y);
    r[6] = (short)f2b(b.z); r[7] = (short)f2b(b.w);
    return r;
}

// ---- init: deg=0, mark=-1, fill=0, cnt=0, etot=0 ----
__global__ __launch_bounds__(256) void init_k(int* deg, int* nid, int* fill,
                                              int* cnt, int* etot) {
    int i = blockIdx.x * 256 + threadIdx.x;
    if (i < N_NODES) { deg[i] = 0; nid[i] = -1; }
    if (i < N_AGENTS) fill[i] = 0;
    if (i == 0) { *cnt = 0; *etot = 0; }
}

// ---- fused: claim marked nodes (first 8192 threads) + in-degree (all edges) ----
__global__ __launch_bounds__(256) void prep1_k(const int* __restrict__ agent_idx,
                                               int* __restrict__ nid,
                                               const int* __restrict__ dst,
                                               int* __restrict__ deg) {
    int i = blockIdx.x * 256 + threadIdx.x;
    if (i < N_AGENTS) atomicCAS(&nid[agent_idx[i]], -1, i);
    if (i < N_EDGES) atomicAdd(&deg[dst[i]], 1);
}

// ---- fused: compact ids + bump-alloc row bases + dis = rsqrt(deg+1) ----
__global__ __launch_bounds__(256) void prep2_k(int* __restrict__ nid,
                                               int* __restrict__ list,
                                               int* __restrict__ cnt,
                                               const int* __restrict__ deg,
                                               int* __restrict__ rowbeg,
                                               int* __restrict__ etot,
                                               float* __restrict__ dis) {
    int i = blockIdx.x * 256 + threadIdx.x;
    if (i < N_NODES) {
        int d = deg[i];
        dis[i] = rsqrtf((float)(d + 1));
        if (nid[i] != -1) {
            int c = atomicAdd(cnt, 1);
            nid[i] = c;
            list[c] = i;
            rowbeg[c] = atomicAdd(etot, d);
        }
    }
}

// ---- fill buckets: for needed dsts, append src to its row ----
__global__ __launch_bounds__(256) void fill_k(const int* __restrict__ src,
                                              const int* __restrict__ dst,
                                              const int* __restrict__ nid,
                                              const int* __restrict__ rowbeg,
                                              int* __restrict__ fill,
                                              int* __restrict__ ebuf) {
    int e = blockIdx.x * 256 + threadIdx.x;
    if (e >= N_EDGES) return;
    int c = nid[dst[e]];
    if (c < 0) return;
    int p = atomicAdd(&fill[c], 1);
    ebuf[rowbeg[c] + p] = src[e];
}

// ---- fused transpose+convert of ALL weights: f32 [K,N] -> bf16 [N,K] ----
__global__ __launch_bounds__(256) void wcvt_k(const float* __restrict__ Wgcn,
                                              const float* __restrict__ W1,
                                              const float* __restrict__ W2,
                                              const float* __restrict__ Wmu,
                                              unsigned short* __restrict__ wgcn_t,
                                              unsigned short* __restrict__ w1_t,
                                              unsigned short* __restrict__ w2_t,
                                              unsigned short* __restrict__ wmu_t) {
    const int s0 = IN_DIM * HID;          // 32768
    const int s1 = HID * FC1;             // 262144
    const int s2 = FC1 * FC2;             // 524288
    const int s3 = FC2 * N_ACT;           // 8192
    int i = blockIdx.x * 256 + threadIdx.x;
    if (i < s0) {
        int k = i / HID, n = i - k * HID;
        wgcn_t[n * IN_DIM + k] = f2b(Wgcn[i]);
    } else if (i < s0 + s1) {
        int j = i - s0;
        int k = j / FC1, n = j - k * FC1;
        w1_t[n * HID + k] = f2b(W1[j]);
    } else if (i < s0 + s1 + s2) {
        int j = i - s0 - s1;
        int k = j / FC2, n = j - k * FC2;
        w2_t[n * FC1 + k] = f2b(W2[j]);
    } else if (i < s0 + s1 + s2 + s3) {
        int j = i - s0 - s1 - s2;
        int k = j / N_ACT, n = j - k * N_ACT;
        wmu_t[n * FC2 + k] = f2b(Wmu[j]);
    }
}

// ---- accumulate per needed node: sum in-edges + self-loop + bias, relu -> bf16 ----
__global__ __launch_bounds__(256) void accum_k(const int* __restrict__ cntp,
                                               const int* __restrict__ list,
                                               const int* __restrict__ rowbeg,
                                               const int* __restrict__ deg,
                                               const int* __restrict__ ebuf,
                                               const float* __restrict__ dis,
                                               const unsigned short* __restrict__ xw,
                                               const float* __restrict__ bgcn,
                                               unsigned short* __restrict__ h_node) {
    int c = blockIdx.x;
    if (c >= *cntp) return;
    int n = list[c];
    int lane = threadIdx.x & 63;
    int wave = threadIdx.x >> 6;
    int beg = rowbeg[c];
    int end = beg + deg[n];
    float dn = dis[n];
    floatx4 acc = {0.0f, 0.0f, 0.0f, 0.0f};
    for (int i = beg + wave; i < end; i += 4) {
        int s = ebuf[i];
        float w = dis[s] * dn;
        ushort4 u = *(const ushort4*)(xw + (size_t)s * HID + lane * 4);
        acc.x += w * b2f(u.x);
        acc.y += w * b2f(u.y);
        acc.z += w * b2f(u.z);
        acc.w += w * b2f(u.w);
    }
    __shared__ float part[4][HID];
    part[wave][lane * 4 + 0] = acc.x;
    part[wave][lane * 4 + 1] = acc.y;
    part[wave][lane * 4 + 2] = acc.z;
    part[wave][lane * 4 + 3] = acc.w;
    __syncthreads();
    int t = threadIdx.x;   // channel 0..255
    float v = part[0][t] + part[1][t] + part[2][t] + part[3][t];
    v += b2f(xw[(size_t)n * HID + t]) * dn * dn + bgcn[t];
    if (v < 0.0f) v = 0.0f;
    h_node[(size_t)c * HID + t] = f2b(v);
}

// ---- gather per agent: copy its node's bf16 row ----
__global__ __launch_bounds__(256) void gather_k(const int* __restrict__ agent_idx,
                                                const int* __restrict__ nid,
                                                const unsigned short* __restrict__ h_node,
                                                unsigned short* __restrict__ h0) {
    int a = blockIdx.x;
    int t = threadIdx.x;
    int c = nid[agent_idx[a]];
    h0[(size_t)a * HID + t] = h_node[(size_t)c * HID + t];
}

// ---- tiled GEMM (bf16 A): C[M,N] = A[M,K] @ Bt[N,K]^T ----
// mode 0: C -> bf16 (outb);  mode 1: C+bias -> f32 (outf)
__global__ __launch_bounds__(256) void gemm_tiled_k(const unsigned short* __restrict__ A,
                                                    const unsigned short* __restrict__ Bt,
                                                    const float* __restrict__ bias,
                                                    unsigned short* __restrict__ outb,
                                                    float* __restrict__ outf,
                                                    int M, int N, int K, int mode) {
    __shared__ unsigned short As[BM][LDK];
    __shared__ unsigned short Bs[BN][LDK];

    int tn = blockIdx.x;
    int tm = blockIdx.y;
    int tid = threadIdx.x;
    int lane = tid & 63;
    int wave = tid >> 6;
    int wm = wave >> 1, wn = wave & 1;
    int r16 = lane & 15, quad = lane >> 4;

    int srow = tid >> 2;
    int scol = (tid & 3) * 8;
    int ar0 = tm * BM + srow;        if (ar0 > M - 1) ar0 = M - 1;
    int ar1 = tm * BM + srow + 64;   if (ar1 > M - 1) ar1 = M - 1;
    int br0 = tn * BN + srow;
    int br1 = tn * BN + srow + 64;
    const unsigned short* pa0 = A + (size_t)ar0 * K + scol;
    const unsigned short* pa1 = A + (size_t)ar1 * K + scol;
    const unsigned short* pb0 = Bt + (size_t)br0 * K + scol;
    const unsigned short* pb1 = Bt + (size_t)br1 * K + scol;

    floatx4 acc[4][4];
    #pragma unroll
    for (int i = 0; i < 4; ++i)
        #pragma unroll
        for (int j = 0; j < 4; ++j)
            acc[i][j] = (floatx4){0.0f, 0.0f, 0.0f, 0.0f};

    bf16x8 ra0 = *(const bf16x8*)pa0;
    bf16x8 ra1 = *(const bf16x8*)pa1;
    bf16x8 rb0 = *(const bf16x8*)pb0;
    bf16x8 rb1 = *(const bf16x8*)pb1;

    for (int k0 = 0; k0 < K; k0 += BK) {
        *(bf16x8*)&As[srow][scol]      = ra0;
        *(bf16x8*)&As[srow + 64][scol] = ra1;
        *(bf16x8*)&Bs[srow][scol]      = rb0;
        *(bf16x8*)&Bs[srow + 64][scol] = rb1;
        __syncthreads();

        if (k0 + BK < K) {
            ra0 = *(const bf16x8*)(pa0 + k0 + BK);
            ra1 = *(const bf16x8*)(pa1 + k0 + BK);
            rb0 = *(const bf16x8*)(pb0 + k0 + BK);
            rb1 = *(const bf16x8*)(pb1 + k0 + BK);
        }

        bf16x8 af[4], bfr[4];
        #pragma unroll
        for (int i = 0; i < 4; ++i)
            af[i] = *(const bf16x8*)&As[wm * 64 + i * 16 + r16][quad * 8];
        #pragma unroll
        for (int j = 0; j < 4; ++j)
            bfr[j] = *(const bf16x8*)&Bs[wn * 64 + j * 16 + r16][quad * 8];
        #pragma unroll
        for (int i = 0; i < 4; ++i)
            #pragma unroll
            for (int j = 0; j < 4; ++j)
                acc[i][j] = __builtin_amdgcn_mfma_f32_16x16x32_bf16(af[i], bfr[j], acc[i][j], 0, 0, 0);
        __syncthreads();
    }

    #pragma unroll
    for (int j = 0; j < 4; ++j) {
        int ocol = tn * BN + wn * 64 + j * 16 + r16;
        float bv = (mode != 0) ? bias[ocol] : 0.0f;
        #pragma unroll
        for (int i = 0; i < 4; ++i) {
            int orow_base = tm * BM + wm * 64 + i * 16 + quad * 4;
            #pragma unroll
            for (int r = 0; r < 4; ++r) {
                int orow = orow_base + r;
                if (orow < M) {
                    size_t idx = (size_t)orow * N + ocol;
                    float v = acc[i][j][r];
                    if (mode == 0) outb[idx] = f2b(v);
                    else           outf[idx] = v + bv;
                }
            }
        }
    }
}

// ---- tiled GEMM with f32 A (converts to bf16 during LDS staging): xw kernel ----
// C -> bf16. Eliminates the separate x-conversion pass.
__global__ __launch_bounds__(256) void gemm_tiled_f32a_k(const float* __restrict__ A,
                                                         const unsigned short* __restrict__ Bt,
                                                         unsigned short* __restrict__ outb,
                                                         int M, int N, int K) {
    __shared__ unsigned short As[BM][LDK];
    __shared__ unsigned short Bs[BN][LDK];

    int tn = blockIdx.x;
    int tm = blockIdx.y;
    int tid = threadIdx.x;
    int lane = tid & 63;
    int wave = tid >> 6;
    int wm = wave >> 1, wn = wave & 1;
    int r16 = lane & 15, quad = lane >> 4;

    int srow = tid >> 2;
    int scol = (tid & 3) * 8;
    int ar0 = tm * BM + srow;        if (ar0 > M - 1) ar0 = M - 1;
    int ar1 = tm * BM + srow + 64;   if (ar1 > M - 1) ar1 = M - 1;
    int br0 = tn * BN + srow;
    int br1 = tn * BN + srow + 64;
    const float* pa0 = A + (size_t)ar0 * K + scol;
    const float* pa1 = A + (size_t)ar1 * K + scol;
    const unsigned short* pb0 = Bt + (size_t)br0 * K + scol;
    const unsigned short* pb1 = Bt + (size_t)br1 * K + scol;

    floatx4 acc[4][4];
    #pragma unroll
    for (int i = 0; i < 4; ++i)
        #pragma unroll
        for (int j = 0; j < 4; ++j)
            acc[i][j] = (floatx4){0.0f, 0.0f, 0.0f, 0.0f};

    float4 ra0a = *(const float4*)pa0, ra0b = *(const float4*)(pa0 + 4);
    float4 ra1a = *(const float4*)pa1, ra1b = *(const float4*)(pa1 + 4);
    bf16x8 rb0 = *(const bf16x8*)pb0;
    bf16x8 rb1 = *(const bf16x8*)pb1;

    for (int k0 = 0; k0 < K; k0 += BK) {
        *(bf16x8*)&As[srow][scol]      = pack8(ra0a, ra0b);
        *(bf16x8*)&As[srow + 64][scol] = pack8(ra1a, ra1b);
        *(bf16x8*)&Bs[srow][scol]      = rb0;
        *(bf16x8*)&Bs[srow + 64][scol] = rb1;
        __syncthreads();

        if (k0 + BK < K) {
            ra0a = *(const float4*)(pa0 + k0 + BK);
            ra0b = *(const float4*)(pa0 + k0 + BK + 4);
            ra1a = *(const float4*)(pa1 + k0 + BK);
            ra1b = *(const float4*)(pa1 + k0 + BK + 4);
            rb0 = *(const bf16x8*)(pb0 + k0 + BK);
            rb1 = *(const bf16x8*)(pb1 + k0 + BK);
        }

        bf16x8 af[4], bfr[4];
        #pragma unroll
        for (int i = 0; i < 4; ++i)
            af[i] = *(const bf16x8*)&As[wm * 64 + i * 16 + r16][quad * 8];
        #pragma unroll
        for (int j = 0; j < 4; ++j)
            bfr[j] = *(const bf16x8*)&Bs[wn * 64 + j * 16 + r16][quad * 8];
        #pragma unroll
        for (int i = 0; i < 4; ++i)
            #pragma unroll
            for (int j = 0; j < 4; ++j)
                acc[i][j] = __builtin_amdgcn_mfma_f32_16x16x32_bf16(af[i], bfr[j], acc[i][j], 0, 0, 0);
        __syncthreads();
    }

    #pragma unroll
    for (int j = 0; j < 4; ++j) {
        int ocol = tn * BN + wn * 64 + j * 16 + r16;
        #pragma unroll
        for (int i = 0; i < 4; ++i) {
            int orow_base = tm * BM + wm * 64 + i * 16 + quad * 4;
            #pragma unroll
            for (int r = 0; r < 4; ++r) {
                int orow = orow_base + r;
                if (orow < M)
                    outb[(size_t)orow * N + ocol] = f2b(acc[i][j][r]);
            }
        }
    }
}

// ---- head: out = sigmoid(h2[8192,512] @ wmu_t[16,512]^T + bmu), K split over 4 waves ----
__global__ __launch_bounds__(256) void head_k(const unsigned short* __restrict__ h2,
                                              const unsigned short* __restrict__ wmu_t,
                                              const float* __restrict__ bmu,
                                              float* __restrict__ out) {
    int blk = blockIdx.x;                 // 512 blocks x 16 rows
    int lane = threadIdx.x & 63;
    int wave = threadIdx.x >> 6;
    int r16 = lane & 15, quad = lane >> 4;
    int row0 = blk * 16;
    const bf16x8* pa = (const bf16x8*)(h2 + (size_t)(row0 + r16) * FC2 + wave * 128 + quad * 8);
    const bf16x8* pb = (const bf16x8*)(wmu_t + (size_t)r16 * FC2 + wave * 128 + quad * 8);
    floatx4 acc = {0.0f, 0.0f, 0.0f, 0.0f};
    #pragma unroll
    for (int s = 0; s < 4; ++s)
        acc = __builtin_amdgcn_mfma_f32_16x16x32_bf16(pa[4 * s], pb[4 * s], acc, 0, 0, 0);
    __shared__ float part[4][64][4];
    #pragma unroll
    for (int r = 0; r < 4; ++r) part[wave][lane][r] = acc[r];
    __syncthreads();
    if (wave == 0) {
        #pragma unroll
        for (int r = 0; r < 4; ++r) {
            float v = part[0][lane][r] + part[1][lane][r] + part[2][lane][r] + part[3][lane][r];
            v += bmu[r16];
            v = 1.0f / (1.0f + expf(-v));
            out[(size_t)(row0 + quad * 4 + r) * N_ACT + r16] = v;
        }
    }
}

// ---- single-pass row LayerNorm (+affine) + relu, f32 in -> bf16 out ----
__global__ __launch_bounds__(256) void ln_relu_k(const float* __restrict__ z,
                                                 const float* __restrict__ g,
                                                 const float* __restrict__ be,
                                                 unsigned short* __restrict__ out, int L) {
    size_t base = (size_t)blockIdx.x * L;
    int nc = L >> 8;                 // 4 (FC1) or 2 (FC2)
    float vreg[4];
    float s = 0.0f, s2 = 0.0f;
    for (int i = 0; i < nc; ++i) {
        float v = z[base + i * 256 + threadIdx.x];
        vreg[i] = v;
        s += v;
        s2 += v * v;
    }
    for (int off = 32; off > 0; off >>= 1) {
        s += __shfl_down(s, off);
        s2 += __shfl_down(s2, off);
    }
    __shared__ float red[8];
    int wave = threadIdx.x >> 6;
    int lane = threadIdx.x & 63;
    if (lane == 0) { red[wave] = s; red[4 + wave] = s2; }
    __syncthreads();
    s  = red[0] + red[1] + red[2] + red[3];
    s2 = red[4] + red[5] + red[6] + red[7];
    float invL = 1.0f / (float)L;
    float mean = s * invL;
    float var = s2 * invL - mean * mean;
    float inv = rsqrtf(var + 1e-5f);
    for (int i = 0; i < nc; ++i) {
        int c = i * 256 + threadIdx.x;
        float v = (vreg[i] - mean) * inv * g[c] + be[c];
        if (v < 0.0f) v = 0.0f;
        out[base + c] = f2b(v);
    }
}

extern "C" void kernel_launch(void* const* d_in, const int* in_sizes, int n_in,
                              void* d_out, int out_size, void* d_ws, size_t ws_size,
                              hipStream_t stream) {
    const float* x    = (const float*)d_in[0];
    const int*   ei   = (const int*)d_in[1];
    const int*   agent= (const int*)d_in[2];
    const float* Wgcn = (const float*)d_in[3];
    const float* bgcn = (const float*)d_in[4];
    const float* W1   = (const float*)d_in[5];
    const float* b1   = (const float*)d_in[6];
    const float* g1   = (const float*)d_in[7];
    const float* be1  = (const float*)d_in[8];
    const float* W2   = (const float*)d_in[9];
    const float* b2   = (const float*)d_in[10];
    const float* g2   = (const float*)d_in[11];
    const float* be2  = (const float*)d_in[12];
    const float* Wmu  = (const float*)d_in[13];
    const float* bmu  = (const float*)d_in[14];
    float* out = (float*)d_out;

    const int* srcp = ei;
    const int* dstp = ei + N_EDGES;

    // workspace layout (256B aligned)
    char* ws = (char*)d_ws;
    size_t off = 0;
    int* deg = (int*)(ws + off);     off += ((size_t)N_NODES * 4 + 255) & ~(size_t)255;
    float* dis = (float*)(ws + off); off += ((size_t)N_NODES * 4 + 255) & ~(size_t)255;
    int* nid = (int*)(ws + off);     off += ((size_t)N_NODES * 4 + 255) & ~(size_t)255;
    int* list = (int*)(ws + off);    off += ((size_t)N_AGENTS * 4 + 255) & ~(size_t)255;
    int* cnt = (int*)(ws + off);     off += 256;
    int* etot = (int*)(ws + off);    off += 256;
    int* rowbeg = (int*)(ws + off);  off += ((size_t)N_AGENTS * 4 + 255) & ~(size_t)255;
    int* fill = (int*)(ws + off);    off += ((size_t)N_AGENTS * 4 + 255) & ~(size_t)255;
    int* ebuf = (int*)(ws + off);    off += ((size_t)N_EDGES * 4 + 255) & ~(size_t)255;
    unsigned short* wgcn_t = (unsigned short*)(ws + off); off += ((size_t)IN_DIM * HID * 2 + 255) & ~(size_t)255;
    unsigned short* w1_t   = (unsigned short*)(ws + off); off += ((size_t)HID * FC1 * 2 + 255) & ~(size_t)255;
    unsigned short* w2_t   = (unsigned short*)(ws + off); off += ((size_t)FC1 * FC2 * 2 + 255) & ~(size_t)255;
    unsigned short* wmu_t  = (unsigned short*)(ws + off); off += ((size_t)FC2 * N_ACT * 2 + 255) & ~(size_t)255;
    unsigned short* xw     = (unsigned short*)(ws + off); off += ((size_t)N_NODES * HID * 2 + 255) & ~(size_t)255;
    unsigned short* h_node = (unsigned short*)(ws + off); off += ((size_t)N_AGENTS * HID * 2 + 255) & ~(size_t)255;
    unsigned short* h0 = (unsigned short*)(ws + off);     off += ((size_t)N_AGENTS * HID * 2 + 255) & ~(size_t)255;
    float* z = (float*)(ws + off);   off += ((size_t)N_AGENTS * FC1 * 4 + 255) & ~(size_t)255;
    unsigned short* h1 = (unsigned short*)(ws + off);     off += ((size_t)N_AGENTS * FC1 * 2 + 255) & ~(size_t)255;
    unsigned short* h2 = (unsigned short*)(ws + off);     off += ((size_t)N_AGENTS * FC2 * 2 + 255) & ~(size_t)255;

    // ---- graph prep / CSR build (scan-free, fused) ----
    init_k<<<(N_NODES + 255) / 256, 256, 0, stream>>>(deg, nid, fill, cnt, etot);
    prep1_k<<<(N_EDGES + 255) / 256, 256, 0, stream>>>(agent, nid, dstp, deg);
    prep2_k<<<(N_NODES + 255) / 256, 256, 0, stream>>>(nid, list, cnt, deg, rowbeg, etot, dis);
    fill_k<<<(N_EDGES + 255) / 256, 256, 0, stream>>>(srcp, dstp, nid, rowbeg, fill, ebuf);

    // ---- all weight transposes in one launch ----
    {
        int total = IN_DIM * HID + HID * FC1 + FC1 * FC2 + FC2 * N_ACT;
        wcvt_k<<<(total + 255) / 256, 256, 0, stream>>>(Wgcn, W1, W2, Wmu,
                                                        wgcn_t, w1_t, w2_t, wmu_t);
    }

    // xw = x @ W_gcn (f32 A converted during staging)
    {
        dim3 grid(HID / BN, (N_NODES + BM - 1) / BM);
        gemm_tiled_f32a_k<<<grid, 256, 0, stream>>>(x, wgcn_t, xw, N_NODES, HID, IN_DIM);
    }

    // per-needed-node aggregation
    accum_k<<<N_AGENTS, 256, 0, stream>>>(cnt, list, rowbeg, deg, ebuf, dis, xw, bgcn, h_node);

    // per-agent gather
    gather_k<<<N_AGENTS, 256, 0, stream>>>(agent, nid, h_node, h0);

    // FC1 -> LN+relu
    {
        dim3 grid(FC1 / BN, N_AGENTS / BM);
        gemm_tiled_k<<<grid, 256, 0, stream>>>(h0, w1_t, b1, (unsigned short*)0, z,
                                               N_AGENTS, FC1, HID, 1);
        ln_relu_k<<<N_AGENTS, 256, 0, stream>>>(z, g1, be1, h1, FC1);
    }

    // FC2 -> LN+relu
    {
        dim3 grid(FC2 / BN, N_AGENTS / BM);
        gemm_tiled_k<<<grid, 256, 0, stream>>>(h1, w2_t, b2, (unsigned short*)0, z,
                                               N_AGENTS, FC2, FC1, 1);
        ln_relu_k<<<N_AGENTS, 256, 0, stream>>>(z, g2, be2, h2, FC2);
    }

    // head: sigmoid(h2 @ Wmu + bmu), K split over waves
    head_k<<<N_AGENTS / 16, 256, 0, stream>>>(h2, wmu_t, bmu, out);
}